// Round 11
// baseline (241.891 us; speedup 1.0000x reference)
//
#include <hip/hip_runtime.h>
#include <math.h>

#define N_PTS 131072
#define BSEG 64
#define CC 256
#define BM 32                    // rows per tile
#define GRID 256                 // persistent blocks (1 per CU)
#define TILES (N_PTS / (GRID * BM))   // 16
#define EXP_SHIFT 4.0f

#define INV_SQRT_DH 0.17677669529663687f  // 1/sqrt(32)

typedef short v8s __attribute__((ext_vector_type(8)));
typedef float v4f __attribute__((ext_vector_type(4)));
typedef int   v4i __attribute__((ext_vector_type(4)));

__device__ __forceinline__ float bf2f(unsigned short h) {
    unsigned u = ((unsigned)h) << 16;
    return __builtin_bit_cast(float, u);
}

__device__ __forceinline__ unsigned short f2bf(float f) {
    unsigned u = __builtin_bit_cast(unsigned, f);
    u += 0x7fffu + ((u >> 16) & 1u);
    return (unsigned short)(u >> 16);
}

__device__ __forceinline__ void split8v(const float* x, v8s* hi, v8s* lo) {
    int h2[4], l2[4];
    #pragma unroll
    for (int i = 0; i < 4; ++i) {
        float a = x[2 * i], b = x[2 * i + 1];
        unsigned short ha = f2bf(a), hb = f2bf(b);
        float ra = a - bf2f(ha), rb = b - bf2f(hb);
        unsigned short la = f2bf(ra), lb = f2bf(rb);
        h2[i] = (int)(((unsigned)hb << 16) | ha);
        l2[i] = (int)(((unsigned)lb << 16) | la);
    }
    *hi = __builtin_bit_cast(v8s, make_int4(h2[0], h2[1], h2[2], h2[3]));
    *lo = __builtin_bit_cast(v8s, make_int4(l2[0], l2[1], l2[2], l2[3]));
}

__device__ __forceinline__ v8s pack8(const float* x) {
    int h2[4];
    #pragma unroll
    for (int i = 0; i < 4; ++i)
        h2[i] = (int)(((unsigned)f2bf(x[2 * i + 1]) << 16) | f2bf(x[2 * i]));
    return __builtin_bit_cast(v8s, make_int4(h2[0], h2[1], h2[2], h2[3]));
}

__device__ __forceinline__ v8s as_v8s(int4 v) { return __builtin_bit_cast(v8s, v); }

// ---------------------------------------------------------------------------
// K1: kps = (k @ Wk^T + bk)/sqrt(DH) ; vp = v @ Wv^T + bv ; zero ssum
// ---------------------------------------------------------------------------
__global__ __launch_bounds__(256) void kv_proj_kernel(
    const float* __restrict__ k, const float* __restrict__ v,
    const float* __restrict__ Wk, const float* __restrict__ bk,
    const float* __restrict__ Wv, const float* __restrict__ bv,
    float* __restrict__ kps, float* __restrict__ vp, float* __restrict__ ssum) {
    int b = blockIdx.x;
    int c = threadIdx.x;
    const float4* krow  = (const float4*)(k + (size_t)b * CC);
    const float4* vrow  = (const float4*)(v + (size_t)b * CC);
    const float4* wkrow = (const float4*)(Wk + (size_t)c * CC);
    const float4* wvrow = (const float4*)(Wv + (size_t)c * CC);
    float accK = 0.f, accV = 0.f;
    #pragma unroll 8
    for (int i = 0; i < CC / 4; ++i) {
        float4 kk = krow[i], wk = wkrow[i];
        accK += kk.x * wk.x + kk.y * wk.y + kk.z * wk.z + kk.w * wk.w;
        float4 vv = vrow[i], wv = wvrow[i];
        accV += vv.x * wv.x + vv.y * wv.y + vv.z * wv.z + vv.w * wv.w;
    }
    kps[b * CC + c] = (accK + bk[c]) * INV_SQRT_DH;
    vp[b * CC + c] = accV + bv[c];
    ssum[b * CC + c] = 0.f;
}

// ---------------------------------------------------------------------------
// K1b: split Wq/Wo into hi/lo bf16 planes, layout W2[p][kf(32)][n(256)][8]
// ---------------------------------------------------------------------------
__global__ __launch_bounds__(256) void wsplit_kernel(
    const float* __restrict__ Wq, const float* __restrict__ Wo,
    short* __restrict__ W2q, short* __restrict__ W2o) {
    int bx = blockIdx.x;
    const float* W = (bx >= 32) ? Wo : Wq;
    short* W2 = (bx >= 32) ? W2o : W2q;
    int kf = bx & 31;
    int n = threadIdx.x;
    const float* src = W + (size_t)n * CC + kf * 8;
    float x[8];
    float4 x0 = *(const float4*)(src);
    float4 x1 = *(const float4*)(src + 4);
    x[0]=x0.x; x[1]=x0.y; x[2]=x0.z; x[3]=x0.w;
    x[4]=x1.x; x[5]=x1.y; x[6]=x1.z; x[7]=x1.w;
    v8s hi, lo;
    split8v(x, &hi, &lo);
    *(v8s*)&W2[((size_t)(0 * 32 + kf) * 256 + n) * 8] = hi;
    *(v8s*)&W2[((size_t)(1 * 32 + kf) * 256 + n) * 8] = lo;
}

// ---------------------------------------------------------------------------
// Persistent deep-pipelined GEMM. 256 blocks x 512 thr (8 waves, 1 block/CU,
// 256-VGPR budget). Wave owns a 32-col strip; its B strip (hi+lo, full K=256)
// lives in 128 VGPRs loaded once. A is staged RAW via global_load_lds into
// double-buffered LDS one tile ahead (pre-swizzled global addresses, linear
// LDS dest); the fp32->bf16 split (MODE0) / p*SV transform (MODE1) run inside
// the K-loop, interleaved with MFMA. 2 barriers/tile; epilogue bounces
// through the (dead) cur buffer for coalesced stores.
// ---------------------------------------------------------------------------
template <int MODE>
__global__ __launch_bounds__(512, 1) void gemm_pipe(
    const void* __restrict__ Ain, const short* __restrict__ W2,
    const float* __restrict__ bias, void* __restrict__ Outv,
    const int* __restrict__ batch, const float* __restrict__ kps,
    const float* __restrict__ SV, float* __restrict__ ssum) {

    constexpr int AB = (MODE == 0) ? 32768 : 16384;   // bytes per buffer
    __shared__ char lds[2 * AB];

    const int tid = threadIdx.x;
    const int lane = tid & 63;
    const int wn = tid >> 6;           // 0..7: 32-col strip
    const int kfl = lane >> 4;         // k-chunk 0..3
    const int rl = lane & 15;          // row (A) / col (B) in fragment
    const int colb = wn * 32;

    v8s Bv[2][8][2];
    #pragma unroll
    for (int p = 0; p < 2; ++p)
        #pragma unroll
        for (int s = 0; s < 8; ++s)
            #pragma unroll
            for (int ni = 0; ni < 2; ++ni)
                Bv[p][s][ni] = as_v8s(*(const int4*)(W2 +
                    ((size_t)(p * 32 + s * 4 + kfl) * 256 + colb + ni * 16 + rl) * 8));

    const float bb0 = bias[colb + rl];
    const float bb1 = bias[colb + 16 + rl];
    const int mbase = blockIdx.x * TILES * BM;

    auto stage_fast = [&](int bsel, int tt) {
        char* base = lds + bsel * AB;
        const int m0 = mbase + tt * BM;
        if (MODE == 0) {
            #pragma unroll
            for (int r = 0; r < 4; ++r) {
                int row = r * 8 + wn;
                int g16 = lane ^ ((row & 15) << 1);
                const float* g = (const float*)Ain + (size_t)(m0 + row) * CC + g16 * 4;
                __builtin_amdgcn_global_load_lds(
                    (const __attribute__((address_space(1))) void*)g,
                    (__attribute__((address_space(3))) void*)(base + row * 1024), 16, 0, 0);
            }
        } else {
            #pragma unroll
            for (int r = 0; r < 2; ++r) {
                int row0 = r * 16 + wn * 2;
                int row = row0 + (lane >> 5);
                int g16 = (lane & 31) ^ (row & 15);
                const unsigned short* g = (const unsigned short*)Ain +
                    (size_t)(m0 + row) * CC + g16 * 8;
                __builtin_amdgcn_global_load_lds(
                    (const __attribute__((address_space(1))) void*)g,
                    (__attribute__((address_space(3))) void*)(base + row0 * 512), 16, 0, 0);
            }
        }
    };
    auto stage_slow = [&](int bsel, int tt) {   // MODE1 only, rare
        char* base = lds + bsel * AB;
        const int m0 = mbase + tt * BM;
        #pragma unroll
        for (int u = 0; u < 2; ++u) {
            int j = tid * 2 + u;
            int row = j >> 5, g16 = j & 31;
            int b = batch[m0 + row];
            v4i praw = *(const v4i*)((const unsigned short*)Ain +
                (size_t)(m0 + row) * CC + g16 * 8);
            v8s p = __builtin_bit_cast(v8s, praw);
            const float* svp = SV + (size_t)b * CC + g16 * 8;
            v4f s0 = *(const v4f*)svp;
            v4f s1 = *(const v4f*)(svp + 4);
            float x[8];
            #pragma unroll
            for (int e = 0; e < 4; ++e) {
                x[e]     = bf2f((unsigned short)p[e]) * s0[e];
                x[4 + e] = bf2f((unsigned short)p[4 + e]) * s1[e];
            }
            *(v8s*)(base + row * 512 + ((g16 ^ (row & 15)) << 4)) = pack8(x);
        }
    };

    {
        bool fast0 = true;
        if (MODE == 1) fast0 = (batch[mbase] == batch[mbase + BM - 1]);
        if (MODE == 1 && !fast0) stage_slow(0, 0); else stage_fast(0, 0);
    }

    for (int t = 0; t < TILES; ++t) {
        const int cur = t & 1;
        char* bc = lds + cur * AB;
        const int m0 = mbase + t * BM;

        __syncthreads();   // barrier A: cur staged, alt free

        if (t + 1 < TILES) {
            bool fastN = true;
            if (MODE == 1)
                fastN = (batch[m0 + BM] == batch[m0 + 2 * BM - 1]);
            if (MODE == 1 && !fastN) stage_slow(cur ^ 1, t + 1);
            else stage_fast(cur ^ 1, t + 1);
        }

        const int bseg = batch[m0];
        const bool fastT = (bseg == batch[m0 + BM - 1]);

        v8s svv[8];
        if (MODE == 1 && fastT) {
            #pragma unroll
            for (int s = 0; s < 8; ++s) {
                const float* svp = SV + (size_t)bseg * CC + (s * 4 + kfl) * 8;
                v4f s0 = *(const v4f*)svp;
                v4f s1 = *(const v4f*)(svp + 4);
                float xx[8] = {s0.x, s0.y, s0.z, s0.w, s1.x, s1.y, s1.z, s1.w};
                svv[s] = pack8(xx);
            }
        }

        v4f acc[2][2];
        #pragma unroll
        for (int i = 0; i < 2; ++i)
            #pragma unroll
            for (int j = 0; j < 2; ++j) acc[i][j] = (v4f){0.f, 0.f, 0.f, 0.f};

        if (MODE == 0) {
            #pragma unroll
            for (int s = 0; s < 8; ++s)
                #pragma unroll
                for (int mi = 0; mi < 2; ++mi) {
                    int row = mi * 16 + rl;
                    int abase = row * 1024 + (((s * 4 + kfl) ^ rl) << 5);
                    v4f x0 = *(const v4f*)(bc + abase);
                    v4f x1 = *(const v4f*)(bc + abase + 16);
                    float x[8] = {x0.x, x0.y, x0.z, x0.w, x1.x, x1.y, x1.z, x1.w};
                    v8s ah, al;
                    split8v(x, &ah, &al);
                    #pragma unroll
                    for (int ni = 0; ni < 2; ++ni) {
                        acc[mi][ni] = __builtin_amdgcn_mfma_f32_16x16x32_bf16(
                            al, Bv[0][s][ni], acc[mi][ni], 0, 0, 0);
                        acc[mi][ni] = __builtin_amdgcn_mfma_f32_16x16x32_bf16(
                            ah, Bv[1][s][ni], acc[mi][ni], 0, 0, 0);
                        acc[mi][ni] = __builtin_amdgcn_mfma_f32_16x16x32_bf16(
                            ah, Bv[0][s][ni], acc[mi][ni], 0, 0, 0);
                    }
                }
        } else if (fastT) {
            #pragma unroll
            for (int s = 0; s < 8; ++s)
                #pragma unroll
                for (int mi = 0; mi < 2; ++mi) {
                    int row = mi * 16 + rl;
                    int abase = row * 512 + ((((s * 4 + kfl) ^ rl) & 31) << 4);
                    v8s p = *(const v8s*)(bc + abase);
                    float x[8];
                    #pragma unroll
                    for (int e = 0; e < 8; ++e)
                        x[e] = bf2f((unsigned short)p[e]) *
                               bf2f((unsigned short)svv[s][e]);
                    v8s a = pack8(x);
                    #pragma unroll
                    for (int ni = 0; ni < 2; ++ni) {
                        acc[mi][ni] = __builtin_amdgcn_mfma_f32_16x16x32_bf16(
                            a, Bv[1][s][ni], acc[mi][ni], 0, 0, 0);
                        acc[mi][ni] = __builtin_amdgcn_mfma_f32_16x16x32_bf16(
                            a, Bv[0][s][ni], acc[mi][ni], 0, 0, 0);
                    }
                }
        } else {
            #pragma unroll
            for (int s = 0; s < 8; ++s)
                #pragma unroll
                for (int mi = 0; mi < 2; ++mi) {
                    int row = mi * 16 + rl;
                    int abase = row * 512 + ((((s * 4 + kfl) ^ rl) & 31) << 4);
                    v8s a = *(const v8s*)(bc + abase);
                    #pragma unroll
                    for (int ni = 0; ni < 2; ++ni) {
                        acc[mi][ni] = __builtin_amdgcn_mfma_f32_16x16x32_bf16(
                            a, Bv[1][s][ni], acc[mi][ni], 0, 0, 0);
                        acc[mi][ni] = __builtin_amdgcn_mfma_f32_16x16x32_bf16(
                            a, Bv[0][s][ni], acc[mi][ni], 0, 0, 0);
                    }
                }
        }

        __syncthreads();   // barrier B: cur reads done -> reuse as bounce

        if (MODE == 0) {
            unsigned short* Ou = (unsigned short*)Outv;
            if (!fastT) {
                int curb = -1;
                float r0 = 0.f, r1 = 0.f;
                #pragma unroll
                for (int mi = 0; mi < 2; ++mi)
                    #pragma unroll
                    for (int r4 = 0; r4 < 4; ++r4) {
                        int row = m0 + mi * 16 + kfl * 4 + r4;
                        int b = batch[row];
                        if (b != curb) {
                            if (curb >= 0) {
                                atomicAdd(&ssum[(size_t)curb * CC + colb + rl], r0);
                                atomicAdd(&ssum[(size_t)curb * CC + colb + 16 + rl], r1);
                                r0 = r1 = 0.f;
                            }
                            curb = b;
                        }
                        float k0 = kps[(size_t)b * CC + colb + rl];
                        float k1 = kps[(size_t)b * CC + colb + 16 + rl];
                        float p0 = __expf((acc[mi][0][r4] + bb0) * k0 - EXP_SHIFT);
                        float p1 = __expf((acc[mi][1][r4] + bb1) * k1 - EXP_SHIFT);
                        Ou[(size_t)row * CC + colb + rl] = f2bf(p0);
                        Ou[(size_t)row * CC + colb + 16 + rl] = f2bf(p1);
                        r0 += p0; r1 += p1;
                    }
                atomicAdd(&ssum[(size_t)curb * CC + colb + rl], r0);
                atomicAdd(&ssum[(size_t)curb * CC + colb + 16 + rl], r1);
            } else {
                float k0 = kps[(size_t)bseg * CC + colb + rl];
                float k1 = kps[(size_t)bseg * CC + colb + 16 + rl];
                float cs0 = 0.f, cs1 = 0.f;
                unsigned short* lwu = (unsigned short*)(bc + wn * 2048);
                #pragma unroll
                for (int mi = 0; mi < 2; ++mi) {
                    #pragma unroll
                    for (int r4 = 0; r4 < 4; ++r4) {
                        float p0 = __expf((acc[mi][0][r4] + bb0) * k0 - EXP_SHIFT);
                        float p1 = __expf((acc[mi][1][r4] + bb1) * k1 - EXP_SHIFT);
                        cs0 += p0; cs1 += p1;
                        lwu[(kfl * 4 + r4) * 40 + rl] = f2bf(p0);
                        lwu[(kfl * 4 + r4) * 40 + 16 + rl] = f2bf(p1);
                    }
                    asm volatile("s_waitcnt lgkmcnt(0)" ::: "memory");
                    int row16 = lane >> 2, chunk = lane & 3;
                    v4i pv = *(const v4i*)&lwu[row16 * 40 + chunk * 8];
                    __builtin_nontemporal_store(pv,
                        (v4i*)&Ou[(size_t)(m0 + mi * 16 + row16) * CC + colb + chunk * 8]);
                    asm volatile("s_waitcnt lgkmcnt(0)" ::: "memory");
                }
                cs0 += __shfl_xor(cs0, 16); cs0 += __shfl_xor(cs0, 32);
                cs1 += __shfl_xor(cs1, 16); cs1 += __shfl_xor(cs1, 32);
                if (kfl == 0) {
                    atomicAdd(&ssum[(size_t)bseg * CC + colb + rl], cs0);
                    atomicAdd(&ssum[(size_t)bseg * CC + colb + 16 + rl], cs1);
                }
            }
        } else {
            float* Of = (float*)Outv;
            float* lwf = (float*)(bc + wn * 2048);
            #pragma unroll
            for (int mi = 0; mi < 2; ++mi)
                #pragma unroll
                for (int c = 0; c < 2; ++c) {
                    if ((kfl >> 1) == c) {
                        #pragma unroll
                        for (int r4 = 0; r4 < 4; ++r4) {
                            lwf[((kfl & 1) * 4 + r4) * 36 + rl] = acc[mi][0][r4] + bb0;
                            lwf[((kfl & 1) * 4 + r4) * 36 + 16 + rl] = acc[mi][1][r4] + bb1;
                        }
                    }
                    asm volatile("s_waitcnt lgkmcnt(0)" ::: "memory");
                    int r = lane >> 3, c4 = lane & 7;
                    v4f pv = *(const v4f*)&lwf[r * 36 + c4 * 4];
                    __builtin_nontemporal_store(pv,
                        (v4f*)&Of[(size_t)(m0 + mi * 16 + c * 8 + r) * CC + colb + c4 * 4]);
                    asm volatile("s_waitcnt lgkmcnt(0)" ::: "memory");
                }
        }
    }
}

// ---------------------------------------------------------------------------
// K_sv: SV[b,c] = vp[b,c] / ssum[b,c]
// ---------------------------------------------------------------------------
__global__ __launch_bounds__(256) void sv_kernel(
    const float* __restrict__ vp, const float* __restrict__ ssum,
    float* __restrict__ SV) {
    int i = blockIdx.x * 256 + threadIdx.x;
    SV[i] = vp[i] / ssum[i];
}

// ---------------------------------------------------------------------------
extern "C" void kernel_launch(void* const* d_in, const int* in_sizes, int n_in,
                              void* d_out, int out_size, void* d_ws, size_t ws_size,
                              hipStream_t stream) {
    const float* q  = (const float*)d_in[0];
    const float* k  = (const float*)d_in[1];
    const float* v  = (const float*)d_in[2];
    const int* batch = (const int*)d_in[3];
    const float* Wq = (const float*)d_in[4];
    const float* bq = (const float*)d_in[5];
    const float* Wk = (const float*)d_in[6];
    const float* bk = (const float*)d_in[7];
    const float* Wv = (const float*)d_in[8];
    const float* bv = (const float*)d_in[9];
    const float* Wo = (const float*)d_in[10];
    const float* bo = (const float*)d_in[11];
    float* out = (float*)d_out;

    char* wsp = (char*)d_ws;
    unsigned short* attn = (unsigned short*)wsp;
    wsp += (size_t)N_PTS * CC * sizeof(unsigned short);                          // 67 MB
    float* kps  = (float*)wsp;  wsp += (size_t)BSEG * CC * sizeof(float);
    float* vp   = (float*)wsp;  wsp += (size_t)BSEG * CC * sizeof(float);
    float* SVb  = (float*)wsp;  wsp += (size_t)BSEG * CC * sizeof(float);
    float* ssum = (float*)wsp;  wsp += (size_t)BSEG * CC * sizeof(float);
    short* W2q  = (short*)wsp;  wsp += (size_t)2 * 32 * 256 * 8 * sizeof(short); // 256 KB
    short* W2o  = (short*)wsp;  wsp += (size_t)2 * 32 * 256 * 8 * sizeof(short);

    kv_proj_kernel<<<BSEG, 256, 0, stream>>>(k, v, Wk, bk, Wv, bv, kps, vp, ssum);
    wsplit_kernel<<<64, 256, 0, stream>>>(Wq, Wo, W2q, W2o);

    gemm_pipe<0><<<GRID, 512, 0, stream>>>(
        (const void*)q, W2q, bq, (void*)attn, batch, kps, nullptr, ssum);

    sv_kernel<<<BSEG, 256, 0, stream>>>(vp, ssum, SVb);

    gemm_pipe<1><<<GRID, 512, 0, stream>>>(
        (const void*)attn, W2o, bo, (void*)out, batch, nullptr, SVb, nullptr);
}

// Round 12
// 188.352 us; speedup vs baseline: 1.2842x; 1.2842x over previous
//
#include <hip/hip_runtime.h>
#include <math.h>

#define N_PTS 131072
#define BSEG 64
#define CC 256
#define BM 32                    // rows per block; A tile (full K) LDS-resident
#define EXP_SHIFT 4.0f

#define INV_SQRT_DH 0.17677669529663687f  // 1/sqrt(32)

typedef short v8s __attribute__((ext_vector_type(8)));
typedef float v4f __attribute__((ext_vector_type(4)));
typedef int   v4i __attribute__((ext_vector_type(4)));

__device__ __forceinline__ float bf2f(unsigned short h) {
    unsigned u = ((unsigned)h) << 16;
    return __builtin_bit_cast(float, u);
}

__device__ __forceinline__ unsigned short f2bf(float f) {
    unsigned u = __builtin_bit_cast(unsigned, f);
    u += 0x7fffu + ((u >> 16) & 1u);
    return (unsigned short)(u >> 16);
}

__device__ __forceinline__ void split8v(const float* x, v8s* hi, v8s* lo) {
    int h2[4], l2[4];
    #pragma unroll
    for (int i = 0; i < 4; ++i) {
        float a = x[2 * i], b = x[2 * i + 1];
        unsigned short ha = f2bf(a), hb = f2bf(b);
        float ra = a - bf2f(ha), rb = b - bf2f(hb);
        unsigned short la = f2bf(ra), lb = f2bf(rb);
        h2[i] = (int)(((unsigned)hb << 16) | ha);
        l2[i] = (int)(((unsigned)lb << 16) | la);
    }
    *hi = __builtin_bit_cast(v8s, make_int4(h2[0], h2[1], h2[2], h2[3]));
    *lo = __builtin_bit_cast(v8s, make_int4(l2[0], l2[1], l2[2], l2[3]));
}

__device__ __forceinline__ v8s pack8(const float* x) {
    int h2[4];
    #pragma unroll
    for (int i = 0; i < 4; ++i)
        h2[i] = (int)(((unsigned)f2bf(x[2 * i + 1]) << 16) | f2bf(x[2 * i]));
    return __builtin_bit_cast(v8s, make_int4(h2[0], h2[1], h2[2], h2[3]));
}

__device__ __forceinline__ v8s as_v8s(int4 v) { return __builtin_bit_cast(v8s, v); }

// ---------------------------------------------------------------------------
// K1: kps = (k @ Wk^T + bk)/sqrt(DH) ; vp = v @ Wv^T + bv ; zero ssum
// ---------------------------------------------------------------------------
__global__ __launch_bounds__(256) void kv_proj_kernel(
    const float* __restrict__ k, const float* __restrict__ v,
    const float* __restrict__ Wk, const float* __restrict__ bk,
    const float* __restrict__ Wv, const float* __restrict__ bv,
    float* __restrict__ kps, float* __restrict__ vp, float* __restrict__ ssum) {
    int b = blockIdx.x;
    int c = threadIdx.x;
    const float4* krow  = (const float4*)(k + (size_t)b * CC);
    const float4* vrow  = (const float4*)(v + (size_t)b * CC);
    const float4* wkrow = (const float4*)(Wk + (size_t)c * CC);
    const float4* wvrow = (const float4*)(Wv + (size_t)c * CC);
    float accK = 0.f, accV = 0.f;
    #pragma unroll 8
    for (int i = 0; i < CC / 4; ++i) {
        float4 kk = krow[i], wk = wkrow[i];
        accK += kk.x * wk.x + kk.y * wk.y + kk.z * wk.z + kk.w * wk.w;
        float4 vv = vrow[i], wv = wvrow[i];
        accV += vv.x * wv.x + vv.y * wv.y + vv.z * wv.z + vv.w * wv.w;
    }
    kps[b * CC + c] = (accK + bk[c]) * INV_SQRT_DH;
    vp[b * CC + c] = accV + bv[c];
    ssum[b * CC + c] = 0.f;
}

// ---------------------------------------------------------------------------
// K1b: split Wq/Wo into hi/lo bf16 planes, layout W2[p][kf(32)][n(256)][8]
// ---------------------------------------------------------------------------
__global__ __launch_bounds__(256) void wsplit_kernel(
    const float* __restrict__ Wq, const float* __restrict__ Wo,
    short* __restrict__ W2q, short* __restrict__ W2o) {
    int bx = blockIdx.x;
    const float* W = (bx >= 32) ? Wo : Wq;
    short* W2 = (bx >= 32) ? W2o : W2q;
    int kf = bx & 31;
    int n = threadIdx.x;
    const float* src = W + (size_t)n * CC + kf * 8;
    float x[8];
    float4 x0 = *(const float4*)(src);
    float4 x1 = *(const float4*)(src + 4);
    x[0]=x0.x; x[1]=x0.y; x[2]=x0.z; x[3]=x0.w;
    x[4]=x1.x; x[5]=x1.y; x[6]=x1.z; x[7]=x1.w;
    v8s hi, lo;
    split8v(x, &hi, &lo);
    *(v8s*)&W2[((size_t)(0 * 32 + kf) * 256 + n) * 8] = hi;
    *(v8s*)&W2[((size_t)(1 * 32 + kf) * 256 + n) * 8] = lo;
}

// ---------------------------------------------------------------------------
// Max-occupancy GEMM: 4096 blocks x 512 thr (8 waves), BM=32 x BN=256.
// __launch_bounds__(512,8) caps VGPR at 64 -> 4 blocks/CU x 8 waves = 32
// waves/CU. No software pipelining: cross-block TLP hides stage/B-load/
// epilogue latency (m114 overlap). 2 barriers/block.
//  MODE 0: A=q fp32 -> split hi/lo LDS planes; 12 MFMA/step/wave.
//          Epilogue: p = exp((acc+bq)*kps[b,c]-4) -> bf16 attn; ssum atomics.
//  MODE 1: A=p bf16, SV-transform at staging; 8 MFMA/step/wave.
//          Epilogue: out = acc + bo (f32) via LDS bounce.
// ---------------------------------------------------------------------------
template <int MODE>
__global__ __launch_bounds__(512, 8) void gemm_hi(
    const void* __restrict__ Ain, const short* __restrict__ W2,
    const float* __restrict__ bias, void* __restrict__ Outv,
    const int* __restrict__ batch, const float* __restrict__ kps,
    const float* __restrict__ SV, float* __restrict__ ssum) {

    constexpr int PL = 16384;   // bytes per plane: 32 rows * 512B
    __shared__ char lds[(MODE == 0) ? 2 * PL : PL];

    const int tid = threadIdx.x;
    const int lane = tid & 63;
    const int wn = tid >> 6;         // 0..7: 32-col strip
    const int kfl = lane >> 4;       // k-chunk 0..3
    const int rl = lane & 15;        // row (A) / col (B) in fragment
    const int colb = wn * 32;
    const int m0 = blockIdx.x * BM;
    const int hsw = ((rl & 7) << 2) | (rl >> 3);

    // ---- stage A tile (2 items of 8 elements per thread) ----
    #pragma unroll
    for (int u = 0; u < 2; ++u) {
        int j = tid * 2 + u;             // 0..1023
        int row = j >> 5;                // 0..31
        int ch = j & 31;                 // 16B chunk (8 cols)
        int h = ((row & 7) << 2) | ((row >> 3) & 1);
        int off = row * 512 + ((ch ^ h) << 4);
        if (MODE == 0) {
            const v4f* ap = (const v4f*)((const float*)Ain +
                (size_t)(m0 + row) * CC + ch * 8);
            v4f x0 = __builtin_nontemporal_load(ap);
            v4f x1 = __builtin_nontemporal_load(ap + 1);
            float x[8] = {x0.x, x0.y, x0.z, x0.w, x1.x, x1.y, x1.z, x1.w};
            v8s hi, lo;
            split8v(x, &hi, &lo);
            *(v8s*)(lds + off) = hi;
            *(v8s*)(lds + PL + off) = lo;
        } else {
            const v4i* ap = (const v4i*)((const unsigned short*)Ain +
                (size_t)(m0 + row) * CC + ch * 8);
            v4i praw = __builtin_nontemporal_load(ap);
            v8s p = __builtin_bit_cast(v8s, praw);
            int b = batch[m0 + row];
            const float* svp = SV + (size_t)b * CC + ch * 8;
            v4f s0 = *(const v4f*)svp;
            v4f s1 = *(const v4f*)(svp + 4);
            float x[8];
            #pragma unroll
            for (int e = 0; e < 4; ++e) {
                x[e]     = bf2f((unsigned short)p[e]) * s0[e];
                x[4 + e] = bf2f((unsigned short)p[4 + e]) * s1[e];
            }
            *(v8s*)(lds + off) = pack8(x);
        }
    }

    v4f acc[2][2];
    #pragma unroll
    for (int i = 0; i < 2; ++i)
        #pragma unroll
        for (int j = 0; j < 2; ++j) acc[i][j] = (v4f){0.f, 0.f, 0.f, 0.f};

    __syncthreads();   // barrier A: tile staged

    // ---- K-loop: B from L2, A from LDS, no prefetch regs (TLP hides) ----
    #pragma unroll
    for (int s = 0; s < 8; ++s) {
        v8s bcur[2][2];
        #pragma unroll
        for (int p = 0; p < 2; ++p)
            #pragma unroll
            for (int ni = 0; ni < 2; ++ni)
                bcur[p][ni] = as_v8s(*(const int4*)(W2 +
                    ((size_t)(p * 32 + s * 4 + kfl) * 256 + colb + ni * 16 + rl) * 8));
        #pragma unroll
        for (int mi = 0; mi < 2; ++mi) {
            int abase = (mi * 16 + rl) * 512 + (((s * 4 + kfl) ^ hsw) << 4);
            if (MODE == 0) {
                v8s ah = *(const v8s*)(lds + abase);
                v8s al = *(const v8s*)(lds + PL + abase);
                #pragma unroll
                for (int ni = 0; ni < 2; ++ni) {
                    acc[mi][ni] = __builtin_amdgcn_mfma_f32_16x16x32_bf16(
                        al, bcur[0][ni], acc[mi][ni], 0, 0, 0);   // lo*hi
                    acc[mi][ni] = __builtin_amdgcn_mfma_f32_16x16x32_bf16(
                        ah, bcur[1][ni], acc[mi][ni], 0, 0, 0);   // hi*lo
                    acc[mi][ni] = __builtin_amdgcn_mfma_f32_16x16x32_bf16(
                        ah, bcur[0][ni], acc[mi][ni], 0, 0, 0);   // hi*hi
                }
            } else {
                v8s a = *(const v8s*)(lds + abase);
                #pragma unroll
                for (int ni = 0; ni < 2; ++ni) {
                    acc[mi][ni] = __builtin_amdgcn_mfma_f32_16x16x32_bf16(
                        a, bcur[1][ni], acc[mi][ni], 0, 0, 0);    // a*lo
                    acc[mi][ni] = __builtin_amdgcn_mfma_f32_16x16x32_bf16(
                        a, bcur[0][ni], acc[mi][ni], 0, 0, 0);    // a*hi
                }
            }
        }
    }

    __syncthreads();   // barrier B: A-LDS dead -> reuse as bounce

    const float bb0 = bias[colb + rl];
    const float bb1 = bias[colb + 16 + rl];

    if (MODE == 0) {
        unsigned short* Ou = (unsigned short*)Outv;
        const int bseg = batch[m0];
        const bool fastT = (bseg == batch[m0 + BM - 1]);
        if (!fastT) {
            // slow path: segment boundary inside tile (rare)
            int curb = -1;
            float r0 = 0.f, r1 = 0.f;
            #pragma unroll
            for (int mi = 0; mi < 2; ++mi)
                #pragma unroll
                for (int r4 = 0; r4 < 4; ++r4) {
                    int row = m0 + mi * 16 + kfl * 4 + r4;
                    int b = batch[row];
                    if (b != curb) {
                        if (curb >= 0) {
                            atomicAdd(&ssum[(size_t)curb * CC + colb + rl], r0);
                            atomicAdd(&ssum[(size_t)curb * CC + colb + 16 + rl], r1);
                            r0 = r1 = 0.f;
                        }
                        curb = b;
                    }
                    float k0 = kps[(size_t)b * CC + colb + rl];
                    float k1 = kps[(size_t)b * CC + colb + 16 + rl];
                    float p0 = __expf((acc[mi][0][r4] + bb0) * k0 - EXP_SHIFT);
                    float p1 = __expf((acc[mi][1][r4] + bb1) * k1 - EXP_SHIFT);
                    Ou[(size_t)row * CC + colb + rl] = f2bf(p0);
                    Ou[(size_t)row * CC + colb + 16 + rl] = f2bf(p1);
                    r0 += p0; r1 += p1;
                }
            atomicAdd(&ssum[(size_t)curb * CC + colb + rl], r0);
            atomicAdd(&ssum[(size_t)curb * CC + colb + 16 + rl], r1);
        } else {
            float k0 = kps[(size_t)bseg * CC + colb + rl];
            float k1 = kps[(size_t)bseg * CC + colb + 16 + rl];
            float cs0 = 0.f, cs1 = 0.f;
            unsigned short* lwu = (unsigned short*)lds + wn * 1024;  // 2KB region
            #pragma unroll
            for (int mi = 0; mi < 2; ++mi) {
                #pragma unroll
                for (int r4 = 0; r4 < 4; ++r4) {
                    float p0 = __expf((acc[mi][0][r4] + bb0) * k0 - EXP_SHIFT);
                    float p1 = __expf((acc[mi][1][r4] + bb1) * k1 - EXP_SHIFT);
                    cs0 += p0; cs1 += p1;
                    lwu[(kfl * 4 + r4) * 40 + rl] = f2bf(p0);
                    lwu[(kfl * 4 + r4) * 40 + 16 + rl] = f2bf(p1);
                }
                asm volatile("s_waitcnt lgkmcnt(0)" ::: "memory");
                int row16 = lane >> 2, chunk = lane & 3;
                v4i pv = *(const v4i*)&lwu[row16 * 40 + chunk * 8];
                __builtin_nontemporal_store(pv,
                    (v4i*)&Ou[(size_t)(m0 + mi * 16 + row16) * CC + colb + chunk * 8]);
                asm volatile("s_waitcnt lgkmcnt(0)" ::: "memory");
            }
            cs0 += __shfl_xor(cs0, 16); cs0 += __shfl_xor(cs0, 32);
            cs1 += __shfl_xor(cs1, 16); cs1 += __shfl_xor(cs1, 32);
            if (kfl == 0) {
                atomicAdd(&ssum[(size_t)bseg * CC + colb + rl], cs0);
                atomicAdd(&ssum[(size_t)bseg * CC + colb + 16 + rl], cs1);
            }
        }
    } else {
        float* Of = (float*)Outv;
        float* lwf = (float*)(lds + wn * 2048);   // 2KB region: 8 rows x 36 f
        #pragma unroll
        for (int mi = 0; mi < 2; ++mi)
            #pragma unroll
            for (int c = 0; c < 2; ++c) {
                if ((kfl >> 1) == c) {
                    #pragma unroll
                    for (int r4 = 0; r4 < 4; ++r4) {
                        lwf[((kfl & 1) * 4 + r4) * 36 + rl] = acc[mi][0][r4] + bb0;
                        lwf[((kfl & 1) * 4 + r4) * 36 + 16 + rl] = acc[mi][1][r4] + bb1;
                    }
                }
                asm volatile("s_waitcnt lgkmcnt(0)" ::: "memory");
                int r = lane >> 3, c4 = lane & 7;
                v4f pv = *(const v4f*)&lwf[r * 36 + c4 * 4];
                __builtin_nontemporal_store(pv,
                    (v4f*)&Of[(size_t)(m0 + mi * 16 + c * 8 + r) * CC + colb + c4 * 4]);
                asm volatile("s_waitcnt lgkmcnt(0)" ::: "memory");
            }
    }
}

// ---------------------------------------------------------------------------
// K_sv: SV[b,c] = vp[b,c] / ssum[b,c]
// ---------------------------------------------------------------------------
__global__ __launch_bounds__(256) void sv_kernel(
    const float* __restrict__ vp, const float* __restrict__ ssum,
    float* __restrict__ SV) {
    int i = blockIdx.x * 256 + threadIdx.x;
    SV[i] = vp[i] / ssum[i];
}

// ---------------------------------------------------------------------------
extern "C" void kernel_launch(void* const* d_in, const int* in_sizes, int n_in,
                              void* d_out, int out_size, void* d_ws, size_t ws_size,
                              hipStream_t stream) {
    const float* q  = (const float*)d_in[0];
    const float* k  = (const float*)d_in[1];
    const float* v  = (const float*)d_in[2];
    const int* batch = (const int*)d_in[3];
    const float* Wq = (const float*)d_in[4];
    const float* bq = (const float*)d_in[5];
    const float* Wk = (const float*)d_in[6];
    const float* bk = (const float*)d_in[7];
    const float* Wv = (const float*)d_in[8];
    const float* bv = (const float*)d_in[9];
    const float* Wo = (const float*)d_in[10];
    const float* bo = (const float*)d_in[11];
    float* out = (float*)d_out;

    char* wsp = (char*)d_ws;
    unsigned short* attn = (unsigned short*)wsp;
    wsp += (size_t)N_PTS * CC * sizeof(unsigned short);                          // 67 MB
    float* kps  = (float*)wsp;  wsp += (size_t)BSEG * CC * sizeof(float);
    float* vp   = (float*)wsp;  wsp += (size_t)BSEG * CC * sizeof(float);
    float* SVb  = (float*)wsp;  wsp += (size_t)BSEG * CC * sizeof(float);
    float* ssum = (float*)wsp;  wsp += (size_t)BSEG * CC * sizeof(float);
    short* W2q  = (short*)wsp;  wsp += (size_t)2 * 32 * 256 * 8 * sizeof(short); // 256 KB
    short* W2o  = (short*)wsp;  wsp += (size_t)2 * 32 * 256 * 8 * sizeof(short);

    kv_proj_kernel<<<BSEG, 256, 0, stream>>>(k, v, Wk, bk, Wv, bv, kps, vp, ssum);
    wsplit_kernel<<<64, 256, 0, stream>>>(Wq, Wo, W2q, W2o);

    gemm_hi<0><<<N_PTS / BM, 512, 0, stream>>>(
        (const void*)q, W2q, bq, (void*)attn, batch, kps, nullptr, ssum);

    sv_kernel<<<BSEG, 256, 0, stream>>>(vp, ssum, SVb);

    gemm_hi<1><<<N_PTS / BM, 512, 0, stream>>>(
        (const void*)attn, W2o, bo, (void*)out, batch, nullptr, SVb, nullptr);
}

// Round 13
// 161.469 us; speedup vs baseline: 1.4981x; 1.1665x over previous
//
#include <hip/hip_runtime.h>
#include <math.h>

#define N_PTS 131072
#define BSEG 64
#define CC 256
#define BM 32                    // rows per block; A tile (full K) LDS-resident
#define EXP_SHIFT 4.0f

#define INV_SQRT_DH 0.17677669529663687f  // 1/sqrt(32)

typedef short v8s __attribute__((ext_vector_type(8)));
typedef float v4f __attribute__((ext_vector_type(4)));
typedef int   v4i __attribute__((ext_vector_type(4)));

__device__ __forceinline__ float bf2f(unsigned short h) {
    unsigned u = ((unsigned)h) << 16;
    return __builtin_bit_cast(float, u);
}

__device__ __forceinline__ unsigned short f2bf(float f) {
    unsigned u = __builtin_bit_cast(unsigned, f);
    u += 0x7fffu + ((u >> 16) & 1u);
    return (unsigned short)(u >> 16);
}

// pack 8 fp32 -> 8 bf16 (RNE)
__device__ __forceinline__ v8s pack8(const float* x) {
    int h2[4];
    #pragma unroll
    for (int i = 0; i < 4; ++i)
        h2[i] = (int)(((unsigned)f2bf(x[2 * i + 1]) << 16) | f2bf(x[2 * i]));
    return __builtin_bit_cast(v8s, make_int4(h2[0], h2[1], h2[2], h2[3]));
}

__device__ __forceinline__ v8s as_v8s(int4 v) { return __builtin_bit_cast(v8s, v); }

// ---------------------------------------------------------------------------
// K1: kps = (k @ Wk^T + bk)/sqrt(DH) ; vp = v @ Wv^T + bv ; zero ssum
// ---------------------------------------------------------------------------
__global__ __launch_bounds__(256) void kv_proj_kernel(
    const float* __restrict__ k, const float* __restrict__ v,
    const float* __restrict__ Wk, const float* __restrict__ bk,
    const float* __restrict__ Wv, const float* __restrict__ bv,
    float* __restrict__ kps, float* __restrict__ vp, float* __restrict__ ssum) {
    int b = blockIdx.x;
    int c = threadIdx.x;
    const float4* krow  = (const float4*)(k + (size_t)b * CC);
    const float4* vrow  = (const float4*)(v + (size_t)b * CC);
    const float4* wkrow = (const float4*)(Wk + (size_t)c * CC);
    const float4* wvrow = (const float4*)(Wv + (size_t)c * CC);
    float accK = 0.f, accV = 0.f;
    #pragma unroll 8
    for (int i = 0; i < CC / 4; ++i) {
        float4 kk = krow[i], wk = wkrow[i];
        accK += kk.x * wk.x + kk.y * wk.y + kk.z * wk.z + kk.w * wk.w;
        float4 vv = vrow[i], wv = wvrow[i];
        accV += vv.x * wv.x + vv.y * wv.y + vv.z * wv.z + vv.w * wv.w;
    }
    kps[b * CC + c] = (accK + bk[c]) * INV_SQRT_DH;
    vp[b * CC + c] = accV + bv[c];
    ssum[b * CC + c] = 0.f;
}

// ---------------------------------------------------------------------------
// K1b: pack Wq/Wo into single bf16 plane, layout W1[kf(32)][n(256)][8]
// ---------------------------------------------------------------------------
__global__ __launch_bounds__(256) void wpack_kernel(
    const float* __restrict__ Wq, const float* __restrict__ Wo,
    short* __restrict__ W1q, short* __restrict__ W1o) {
    int bx = blockIdx.x;                 // 0..63
    const float* W = (bx >= 32) ? Wo : Wq;
    short* W1 = (bx >= 32) ? W1o : W1q;
    int kf = bx & 31;
    int n = threadIdx.x;
    const float* src = W + (size_t)n * CC + kf * 8;
    float4 x0 = *(const float4*)(src);
    float4 x1 = *(const float4*)(src + 4);
    float x[8] = {x0.x, x0.y, x0.z, x0.w, x1.x, x1.y, x1.z, x1.w};
    *(v8s*)&W1[((size_t)kf * 256 + n) * 8] = pack8(x);
}

// ---------------------------------------------------------------------------
// Single-plane bf16 GEMM: 4096 blocks x 512 thr (8 waves), BM=32 x BN=256.
// __launch_bounds__(512,4): 128-VGPR budget. Wave owns a 32-col strip; its B
// strip (single bf16 plane, full K=256) = 16 v8s = 64 VGPR, loaded ONCE.
// A staged to a single 16 KB LDS plane; K-loop = pure ds_read + 1 MFMA chain.
//  MODE 0: A=q fp32 -> bf16. p = exp((acc+bq)*kps[b,c]-4) -> bf16 attn;
//          segment colsum -> ssum atomics.
//  MODE 1: A=p bf16, SV-transform at staging. Out = acc + bo (f32).
// ---------------------------------------------------------------------------
template <int MODE>
__global__ __launch_bounds__(512, 4) void gemm_s(
    const void* __restrict__ Ain, const short* __restrict__ W1,
    const float* __restrict__ bias, void* __restrict__ Outv,
    const int* __restrict__ batch, const float* __restrict__ kps,
    const float* __restrict__ SV, float* __restrict__ ssum) {

    __shared__ char lds[16384];      // 32 rows * 512B (bf16 plane)

    const int tid = threadIdx.x;
    const int lane = tid & 63;
    const int wn = tid >> 6;         // 0..7: 32-col strip
    const int kfl = lane >> 4;       // k-chunk 0..3
    const int rl = lane & 15;        // row (A) / col (B) in fragment
    const int colb = wn * 32;
    const int m0 = blockIdx.x * BM;
    const int hsw = ((rl & 7) << 2) | (rl >> 3);

    // ---- B strip resident in VGPRs: 16 x v8s = 64 VGPR, loaded once ----
    v8s Bv[8][2];
    #pragma unroll
    for (int s = 0; s < 8; ++s)
        #pragma unroll
        for (int ni = 0; ni < 2; ++ni)
            Bv[s][ni] = as_v8s(*(const int4*)(W1 +
                ((size_t)(s * 4 + kfl) * 256 + colb + ni * 16 + rl) * 8));

    // ---- stage A tile (2 items of 8 elements per thread) ----
    #pragma unroll
    for (int u = 0; u < 2; ++u) {
        int j = tid * 2 + u;             // 0..1023
        int row = j >> 5;                // 0..31
        int ch = j & 31;                 // 16B chunk (8 cols)
        int h = ((row & 7) << 2) | ((row >> 3) & 1);
        int off = row * 512 + ((ch ^ h) << 4);
        if (MODE == 0) {
            const v4f* ap = (const v4f*)((const float*)Ain +
                (size_t)(m0 + row) * CC + ch * 8);
            v4f x0 = __builtin_nontemporal_load(ap);
            v4f x1 = __builtin_nontemporal_load(ap + 1);
            float x[8] = {x0.x, x0.y, x0.z, x0.w, x1.x, x1.y, x1.z, x1.w};
            *(v8s*)(lds + off) = pack8(x);
        } else {
            const v4i* ap = (const v4i*)((const unsigned short*)Ain +
                (size_t)(m0 + row) * CC + ch * 8);
            v4i praw = __builtin_nontemporal_load(ap);
            v8s p = __builtin_bit_cast(v8s, praw);
            int b = batch[m0 + row];
            const float* svp = SV + (size_t)b * CC + ch * 8;
            v4f s0 = *(const v4f*)svp;
            v4f s1 = *(const v4f*)(svp + 4);
            float x[8];
            #pragma unroll
            for (int e = 0; e < 4; ++e) {
                x[e]     = bf2f((unsigned short)p[e]) * s0[e];
                x[4 + e] = bf2f((unsigned short)p[4 + e]) * s1[e];
            }
            *(v8s*)(lds + off) = pack8(x);
        }
    }

    v4f acc[2][2];
    #pragma unroll
    for (int i = 0; i < 2; ++i)
        #pragma unroll
        for (int j = 0; j < 2; ++j) acc[i][j] = (v4f){0.f, 0.f, 0.f, 0.f};

    __syncthreads();   // barrier A: tile staged

    // ---- K-loop: pure LDS + MFMA (B already in registers) ----
    #pragma unroll
    for (int s = 0; s < 8; ++s)
        #pragma unroll
        for (int mi = 0; mi < 2; ++mi) {
            int abase = (mi * 16 + rl) * 512 + (((s * 4 + kfl) ^ hsw) << 4);
            v8s a = *(const v8s*)(lds + abase);
            #pragma unroll
            for (int ni = 0; ni < 2; ++ni)
                acc[mi][ni] = __builtin_amdgcn_mfma_f32_16x16x32_bf16(
                    a, Bv[s][ni], acc[mi][ni], 0, 0, 0);
        }

    __syncthreads();   // barrier B: A-LDS dead -> reuse as bounce

    const float bb0 = bias[colb + rl];
    const float bb1 = bias[colb + 16 + rl];

    if (MODE == 0) {
        unsigned short* Ou = (unsigned short*)Outv;
        const int bseg = batch[m0];
        const bool fastT = (bseg == batch[m0 + BM - 1]);
        if (!fastT) {
            // slow path: segment boundary inside tile (rare)
            int curb = -1;
            float r0 = 0.f, r1 = 0.f;
            #pragma unroll
            for (int mi = 0; mi < 2; ++mi)
                #pragma unroll
                for (int r4 = 0; r4 < 4; ++r4) {
                    int row = m0 + mi * 16 + kfl * 4 + r4;
                    int b = batch[row];
                    if (b != curb) {
                        if (curb >= 0) {
                            atomicAdd(&ssum[(size_t)curb * CC + colb + rl], r0);
                            atomicAdd(&ssum[(size_t)curb * CC + colb + 16 + rl], r1);
                            r0 = r1 = 0.f;
                        }
                        curb = b;
                    }
                    float k0 = kps[(size_t)b * CC + colb + rl];
                    float k1 = kps[(size_t)b * CC + colb + 16 + rl];
                    float p0 = __expf((acc[mi][0][r4] + bb0) * k0 - EXP_SHIFT);
                    float p1 = __expf((acc[mi][1][r4] + bb1) * k1 - EXP_SHIFT);
                    Ou[(size_t)row * CC + colb + rl] = f2bf(p0);
                    Ou[(size_t)row * CC + colb + 16 + rl] = f2bf(p1);
                    r0 += p0; r1 += p1;
                }
            atomicAdd(&ssum[(size_t)curb * CC + colb + rl], r0);
            atomicAdd(&ssum[(size_t)curb * CC + colb + 16 + rl], r1);
        } else {
            float k0 = kps[(size_t)bseg * CC + colb + rl];
            float k1 = kps[(size_t)bseg * CC + colb + 16 + rl];
            float cs0 = 0.f, cs1 = 0.f;
            unsigned short* lwu = (unsigned short*)lds + wn * 1024;  // 2KB region
            #pragma unroll
            for (int mi = 0; mi < 2; ++mi) {
                #pragma unroll
                for (int r4 = 0; r4 < 4; ++r4) {
                    float p0 = __expf((acc[mi][0][r4] + bb0) * k0 - EXP_SHIFT);
                    float p1 = __expf((acc[mi][1][r4] + bb1) * k1 - EXP_SHIFT);
                    cs0 += p0; cs1 += p1;
                    lwu[(kfl * 4 + r4) * 40 + rl] = f2bf(p0);
                    lwu[(kfl * 4 + r4) * 40 + 16 + rl] = f2bf(p1);
                }
                asm volatile("s_waitcnt lgkmcnt(0)" ::: "memory");
                int row16 = lane >> 2, chunk = lane & 3;
                v4i pv = *(const v4i*)&lwu[row16 * 40 + chunk * 8];
                __builtin_nontemporal_store(pv,
                    (v4i*)&Ou[(size_t)(m0 + mi * 16 + row16) * CC + colb + chunk * 8]);
                asm volatile("s_waitcnt lgkmcnt(0)" ::: "memory");
            }
            cs0 += __shfl_xor(cs0, 16); cs0 += __shfl_xor(cs0, 32);
            cs1 += __shfl_xor(cs1, 16); cs1 += __shfl_xor(cs1, 32);
            if (kfl == 0) {
                atomicAdd(&ssum[(size_t)bseg * CC + colb + rl], cs0);
                atomicAdd(&ssum[(size_t)bseg * CC + colb + 16 + rl], cs1);
            }
        }
    } else {
        float* Of = (float*)Outv;
        float* lwf = (float*)(lds + wn * 2048);   // 2KB region: 8 rows x 36 f
        #pragma unroll
        for (int mi = 0; mi < 2; ++mi)
            #pragma unroll
            for (int c = 0; c < 2; ++c) {
                if ((kfl >> 1) == c) {
                    #pragma unroll
                    for (int r4 = 0; r4 < 4; ++r4) {
                        lwf[((kfl & 1) * 4 + r4) * 36 + rl] = acc[mi][0][r4] + bb0;
                        lwf[((kfl & 1) * 4 + r4) * 36 + 16 + rl] = acc[mi][1][r4] + bb1;
                    }
                }
                asm volatile("s_waitcnt lgkmcnt(0)" ::: "memory");
                int r = lane >> 3, c4 = lane & 7;
                v4f pv = *(const v4f*)&lwf[r * 36 + c4 * 4];
                __builtin_nontemporal_store(pv,
                    (v4f*)&Of[(size_t)(m0 + mi * 16 + c * 8 + r) * CC + colb + c4 * 4]);
                asm volatile("s_waitcnt lgkmcnt(0)" ::: "memory");
            }
    }
}

// ---------------------------------------------------------------------------
// K_sv: SV[b,c] = vp[b,c] / ssum[b,c]
// ---------------------------------------------------------------------------
__global__ __launch_bounds__(256) void sv_kernel(
    const float* __restrict__ vp, const float* __restrict__ ssum,
    float* __restrict__ SV) {
    int i = blockIdx.x * 256 + threadIdx.x;
    SV[i] = vp[i] / ssum[i];
}

// ---------------------------------------------------------------------------
extern "C" void kernel_launch(void* const* d_in, const int* in_sizes, int n_in,
                              void* d_out, int out_size, void* d_ws, size_t ws_size,
                              hipStream_t stream) {
    const float* q  = (const float*)d_in[0];
    const float* k  = (const float*)d_in[1];
    const float* v  = (const float*)d_in[2];
    const int* batch = (const int*)d_in[3];
    const float* Wq = (const float*)d_in[4];
    const float* bq = (const float*)d_in[5];
    const float* Wk = (const float*)d_in[6];
    const float* bk = (const float*)d_in[7];
    const float* Wv = (const float*)d_in[8];
    const float* bv = (const float*)d_in[9];
    const float* Wo = (const float*)d_in[10];
    const float* bo = (const float*)d_in[11];
    float* out = (float*)d_out;

    char* wsp = (char*)d_ws;
    unsigned short* attn = (unsigned short*)wsp;
    wsp += (size_t)N_PTS * CC * sizeof(unsigned short);                          // 67 MB
    float* kps  = (float*)wsp;  wsp += (size_t)BSEG * CC * sizeof(float);
    float* vp   = (float*)wsp;  wsp += (size_t)BSEG * CC * sizeof(float);
    float* SVb  = (float*)wsp;  wsp += (size_t)BSEG * CC * sizeof(float);
    float* ssum = (float*)wsp;  wsp += (size_t)BSEG * CC * sizeof(float);
    short* W1q  = (short*)wsp;  wsp += (size_t)32 * 256 * 8 * sizeof(short);     // 128 KB
    short* W1o  = (short*)wsp;  wsp += (size_t)32 * 256 * 8 * sizeof(short);

    kv_proj_kernel<<<BSEG, 256, 0, stream>>>(k, v, Wk, bk, Wv, bv, kps, vp, ssum);
    wpack_kernel<<<64, 256, 0, stream>>>(Wq, Wo, W1q, W1o);

    gemm_s<0><<<N_PTS / BM, 512, 0, stream>>>(
        (const void*)q, W1q, bq, (void*)attn, batch, kps, nullptr, ssum);

    sv_kernel<<<BSEG, 256, 0, stream>>>(vp, ssum, SVb);

    gemm_s<1><<<N_PTS / BM, 512, 0, stream>>>(
        (const void*)attn, W1o, bo, (void*)out, batch, nullptr, SVb, nullptr);
}

// Round 14
// 151.417 us; speedup vs baseline: 1.5975x; 1.0664x over previous
//
#include <hip/hip_runtime.h>
#include <math.h>

#define N_PTS 131072
#define BSEG 64
#define CC 256
#define BM 32                    // rows per tile
#define TILES 4                  // tiles per persistent block (B reuse)
#define GRID (N_PTS / (BM * TILES))   // 1024 blocks
#define EXP_SHIFT 4.0f

#define INV_SQRT_DH 0.17677669529663687f  // 1/sqrt(32)

typedef short v8s __attribute__((ext_vector_type(8)));
typedef float v4f __attribute__((ext_vector_type(4)));
typedef int   v4i __attribute__((ext_vector_type(4)));

__device__ __forceinline__ float bf2f(unsigned short h) {
    unsigned u = ((unsigned)h) << 16;
    return __builtin_bit_cast(float, u);
}

__device__ __forceinline__ unsigned short f2bf(float f) {
    unsigned u = __builtin_bit_cast(unsigned, f);
    u += 0x7fffu + ((u >> 16) & 1u);
    return (unsigned short)(u >> 16);
}

// pack 8 fp32 -> 8 bf16 (RNE)
__device__ __forceinline__ v8s pack8(const float* x) {
    int h2[4];
    #pragma unroll
    for (int i = 0; i < 4; ++i)
        h2[i] = (int)(((unsigned)f2bf(x[2 * i + 1]) << 16) | f2bf(x[2 * i]));
    return __builtin_bit_cast(v8s, make_int4(h2[0], h2[1], h2[2], h2[3]));
}

__device__ __forceinline__ v8s as_v8s(int4 v) { return __builtin_bit_cast(v8s, v); }

// opaque pass-through: makes the value un-rematerializable (pins it live)
__device__ __forceinline__ v8s pin(v8s x) {
    v4i t = __builtin_bit_cast(v4i, x);
    asm volatile("" : "+v"(t));
    return __builtin_bit_cast(v8s, t);
}

// ---------------------------------------------------------------------------
// K1: kps = (k @ Wk^T + bk)/sqrt(DH) ; vp = v @ Wv^T + bv ; zero ssum
// ---------------------------------------------------------------------------
__global__ __launch_bounds__(256) void kv_proj_kernel(
    const float* __restrict__ k, const float* __restrict__ v,
    const float* __restrict__ Wk, const float* __restrict__ bk,
    const float* __restrict__ Wv, const float* __restrict__ bv,
    float* __restrict__ kps, float* __restrict__ vp, float* __restrict__ ssum) {
    int b = blockIdx.x;
    int c = threadIdx.x;
    const float4* krow  = (const float4*)(k + (size_t)b * CC);
    const float4* vrow  = (const float4*)(v + (size_t)b * CC);
    const float4* wkrow = (const float4*)(Wk + (size_t)c * CC);
    const float4* wvrow = (const float4*)(Wv + (size_t)c * CC);
    float accK = 0.f, accV = 0.f;
    #pragma unroll 8
    for (int i = 0; i < CC / 4; ++i) {
        float4 kk = krow[i], wk = wkrow[i];
        accK += kk.x * wk.x + kk.y * wk.y + kk.z * wk.z + kk.w * wk.w;
        float4 vv = vrow[i], wv = wvrow[i];
        accV += vv.x * wv.x + vv.y * wv.y + vv.z * wv.z + vv.w * wv.w;
    }
    kps[b * CC + c] = (accK + bk[c]) * INV_SQRT_DH;
    vp[b * CC + c] = accV + bv[c];
    ssum[b * CC + c] = 0.f;
}

// ---------------------------------------------------------------------------
// K1b: pack Wq/Wo into single bf16 plane, layout W1[kf(32)][n(256)][8]
// ---------------------------------------------------------------------------
__global__ __launch_bounds__(256) void wpack_kernel(
    const float* __restrict__ Wq, const float* __restrict__ Wo,
    short* __restrict__ W1q, short* __restrict__ W1o) {
    int bx = blockIdx.x;                 // 0..63
    const float* W = (bx >= 32) ? Wo : Wq;
    short* W1 = (bx >= 32) ? W1o : W1q;
    int kf = bx & 31;
    int n = threadIdx.x;
    const float* src = W + (size_t)n * CC + kf * 8;
    float4 x0 = *(const float4*)(src);
    float4 x1 = *(const float4*)(src + 4);
    float x[8] = {x0.x, x0.y, x0.z, x0.w, x1.x, x1.y, x1.z, x1.w};
    *(v8s*)&W1[((size_t)kf * 256 + n) * 8] = pack8(x);
}

// ---------------------------------------------------------------------------
// Persistent single-plane bf16 GEMM: 1024 blocks x 512 thr (8 waves),
// TILES=4 x BM=32 rows each, BN=256. Wave owns a 32-col strip; its B strip
// (single bf16 plane, full K=256) = 16 v8s = 64 VGPR, loaded ONCE and PINNED
// (asm pass-through defeats remat), reused 4 tiles. K-loop = ds_read + MFMA.
//  MODE 0: A=q fp32 -> bf16. p = exp((acc+bq)*kps[b,c]-4) -> bf16 attn;
//          segment colsum -> ssum atomics.
//  MODE 1: A=p bf16, SV-transform at staging. Out = acc + bo (f32).
// ---------------------------------------------------------------------------
template <int MODE>
__global__ __launch_bounds__(512, 4) void gemm_p(
    const void* __restrict__ Ain, const short* __restrict__ W1,
    const float* __restrict__ bias, void* __restrict__ Outv,
    const int* __restrict__ batch, const float* __restrict__ kps,
    const float* __restrict__ SV, float* __restrict__ ssum) {

    __shared__ char lds[16384];      // 32 rows * 512B (bf16 plane)

    const int tid = threadIdx.x;
    const int lane = tid & 63;
    const int wn = tid >> 6;         // 0..7: 32-col strip
    const int kfl = lane >> 4;       // k-chunk 0..3
    const int rl = lane & 15;        // row (A) / col (B) in fragment
    const int colb = wn * 32;
    const int hsw = ((rl & 7) << 2) | (rl >> 3);

    // ---- B strip resident in VGPRs: 16 x v8s = 64 VGPR, loaded once ----
    v8s Bv[8][2];
    #pragma unroll
    for (int s = 0; s < 8; ++s)
        #pragma unroll
        for (int ni = 0; ni < 2; ++ni)
            Bv[s][ni] = pin(as_v8s(*(const int4*)(W1 +
                ((size_t)(s * 4 + kfl) * 256 + colb + ni * 16 + rl) * 8)));

    const float bb0 = bias[colb + rl];
    const float bb1 = bias[colb + 16 + rl];
    const int mbase = blockIdx.x * TILES * BM;

    for (int t = 0; t < TILES; ++t) {
        const int m0 = mbase + t * BM;
        if (t) __syncthreads();   // prev epilogue LDS reads done

        // ---- stage A tile (2 items of 8 elements per thread) ----
        #pragma unroll
        for (int u = 0; u < 2; ++u) {
            int j = tid * 2 + u;             // 0..1023
            int row = j >> 5;                // 0..31
            int ch = j & 31;                 // 16B chunk (8 cols)
            int h = ((row & 7) << 2) | ((row >> 3) & 1);
            int off = row * 512 + ((ch ^ h) << 4);
            if (MODE == 0) {
                const v4f* ap = (const v4f*)((const float*)Ain +
                    (size_t)(m0 + row) * CC + ch * 8);
                v4f x0 = __builtin_nontemporal_load(ap);
                v4f x1 = __builtin_nontemporal_load(ap + 1);
                float x[8] = {x0.x, x0.y, x0.z, x0.w, x1.x, x1.y, x1.z, x1.w};
                *(v8s*)(lds + off) = pack8(x);
            } else {
                const v4i* ap = (const v4i*)((const unsigned short*)Ain +
                    (size_t)(m0 + row) * CC + ch * 8);
                v4i praw = __builtin_nontemporal_load(ap);
                v8s p = __builtin_bit_cast(v8s, praw);
                int b = batch[m0 + row];
                const float* svp = SV + (size_t)b * CC + ch * 8;
                v4f s0 = *(const v4f*)svp;
                v4f s1 = *(const v4f*)(svp + 4);
                float x[8];
                #pragma unroll
                for (int e = 0; e < 4; ++e) {
                    x[e]     = bf2f((unsigned short)p[e]) * s0[e];
                    x[4 + e] = bf2f((unsigned short)p[4 + e]) * s1[e];
                }
                *(v8s*)(lds + off) = pack8(x);
            }
        }

        v4f acc[2][2];
        #pragma unroll
        for (int i = 0; i < 2; ++i)
            #pragma unroll
            for (int j = 0; j < 2; ++j) acc[i][j] = (v4f){0.f, 0.f, 0.f, 0.f};

        __syncthreads();   // barrier A: tile staged

        // ---- K-loop: pure LDS + MFMA (B pinned in registers) ----
        #pragma unroll
        for (int s = 0; s < 8; ++s)
            #pragma unroll
            for (int mi = 0; mi < 2; ++mi) {
                int abase = (mi * 16 + rl) * 512 + (((s * 4 + kfl) ^ hsw) << 4);
                v8s a = *(const v8s*)(lds + abase);
                #pragma unroll
                for (int ni = 0; ni < 2; ++ni)
                    acc[mi][ni] = __builtin_amdgcn_mfma_f32_16x16x32_bf16(
                        a, Bv[s][ni], acc[mi][ni], 0, 0, 0);
            }

        __syncthreads();   // barrier B: A-LDS dead -> reuse as bounce

        if (MODE == 0) {
            unsigned short* Ou = (unsigned short*)Outv;
            const int bseg = batch[m0];
            const bool fastT = (bseg == batch[m0 + BM - 1]);
            if (!fastT) {
                // slow path: segment boundary inside tile (rare)
                int curb = -1;
                float r0 = 0.f, r1 = 0.f;
                #pragma unroll
                for (int mi = 0; mi < 2; ++mi)
                    #pragma unroll
                    for (int r4 = 0; r4 < 4; ++r4) {
                        int row = m0 + mi * 16 + kfl * 4 + r4;
                        int b = batch[row];
                        if (b != curb) {
                            if (curb >= 0) {
                                atomicAdd(&ssum[(size_t)curb * CC + colb + rl], r0);
                                atomicAdd(&ssum[(size_t)curb * CC + colb + 16 + rl], r1);
                                r0 = r1 = 0.f;
                            }
                            curb = b;
                        }
                        float k0 = kps[(size_t)b * CC + colb + rl];
                        float k1 = kps[(size_t)b * CC + colb + 16 + rl];
                        float p0 = __expf((acc[mi][0][r4] + bb0) * k0 - EXP_SHIFT);
                        float p1 = __expf((acc[mi][1][r4] + bb1) * k1 - EXP_SHIFT);
                        Ou[(size_t)row * CC + colb + rl] = f2bf(p0);
                        Ou[(size_t)row * CC + colb + 16 + rl] = f2bf(p1);
                        r0 += p0; r1 += p1;
                    }
                atomicAdd(&ssum[(size_t)curb * CC + colb + rl], r0);
                atomicAdd(&ssum[(size_t)curb * CC + colb + 16 + rl], r1);
            } else {
                float k0 = kps[(size_t)bseg * CC + colb + rl];
                float k1 = kps[(size_t)bseg * CC + colb + 16 + rl];
                float cs0 = 0.f, cs1 = 0.f;
                unsigned short* lwu = (unsigned short*)lds + wn * 1024;  // 2KB region
                #pragma unroll
                for (int mi = 0; mi < 2; ++mi) {
                    #pragma unroll
                    for (int r4 = 0; r4 < 4; ++r4) {
                        float p0 = __expf((acc[mi][0][r4] + bb0) * k0 - EXP_SHIFT);
                        float p1 = __expf((acc[mi][1][r4] + bb1) * k1 - EXP_SHIFT);
                        cs0 += p0; cs1 += p1;
                        lwu[(kfl * 4 + r4) * 40 + rl] = f2bf(p0);
                        lwu[(kfl * 4 + r4) * 40 + 16 + rl] = f2bf(p1);
                    }
                    asm volatile("s_waitcnt lgkmcnt(0)" ::: "memory");
                    int row16 = lane >> 2, chunk = lane & 3;
                    v4i pv = *(const v4i*)&lwu[row16 * 40 + chunk * 8];
                    __builtin_nontemporal_store(pv,
                        (v4i*)&Ou[(size_t)(m0 + mi * 16 + row16) * CC + colb + chunk * 8]);
                    asm volatile("s_waitcnt lgkmcnt(0)" ::: "memory");
                }
                cs0 += __shfl_xor(cs0, 16); cs0 += __shfl_xor(cs0, 32);
                cs1 += __shfl_xor(cs1, 16); cs1 += __shfl_xor(cs1, 32);
                if (kfl == 0) {
                    atomicAdd(&ssum[(size_t)bseg * CC + colb + rl], cs0);
                    atomicAdd(&ssum[(size_t)bseg * CC + colb + 16 + rl], cs1);
                }
            }
        } else {
            float* Of = (float*)Outv;
            float* lwf = (float*)(lds + wn * 2048);   // 2KB region: 8 rows x 36 f
            #pragma unroll
            for (int mi = 0; mi < 2; ++mi)
                #pragma unroll
                for (int c = 0; c < 2; ++c) {
                    if ((kfl >> 1) == c) {
                        #pragma unroll
                        for (int r4 = 0; r4 < 4; ++r4) {
                            lwf[((kfl & 1) * 4 + r4) * 36 + rl] = acc[mi][0][r4] + bb0;
                            lwf[((kfl & 1) * 4 + r4) * 36 + 16 + rl] = acc[mi][1][r4] + bb1;
                        }
                    }
                    asm volatile("s_waitcnt lgkmcnt(0)" ::: "memory");
                    int r = lane >> 3, c4 = lane & 7;
                    v4f pv = *(const v4f*)&lwf[r * 36 + c4 * 4];
                    __builtin_nontemporal_store(pv,
                        (v4f*)&Of[(size_t)(m0 + mi * 16 + c * 8 + r) * CC + colb + c4 * 4]);
                    asm volatile("s_waitcnt lgkmcnt(0)" ::: "memory");
                }
        }
    }
}

// ---------------------------------------------------------------------------
// K_sv: SV[b,c] = vp[b,c] / ssum[b,c]
// ---------------------------------------------------------------------------
__global__ __launch_bounds__(256) void sv_kernel(
    const float* __restrict__ vp, const float* __restrict__ ssum,
    float* __restrict__ SV) {
    int i = blockIdx.x * 256 + threadIdx.x;
    SV[i] = vp[i] / ssum[i];
}

// ---------------------------------------------------------------------------
extern "C" void kernel_launch(void* const* d_in, const int* in_sizes, int n_in,
                              void* d_out, int out_size, void* d_ws, size_t ws_size,
                              hipStream_t stream) {
    const float* q  = (const float*)d_in[0];
    const float* k  = (const float*)d_in[1];
    const float* v  = (const float*)d_in[2];
    const int* batch = (const int*)d_in[3];
    const float* Wq = (const float*)d_in[4];
    const float* bq = (const float*)d_in[5];
    const float* Wk = (const float*)d_in[6];
    const float* bk = (const float*)d_in[7];
    const float* Wv = (const float*)d_in[8];
    const float* bv = (const float*)d_in[9];
    const float* Wo = (const float*)d_in[10];
    const float* bo = (const float*)d_in[11];
    float* out = (float*)d_out;

    char* wsp = (char*)d_ws;
    unsigned short* attn = (unsigned short*)wsp;
    wsp += (size_t)N_PTS * CC * sizeof(unsigned short);                          // 67 MB
    float* kps  = (float*)wsp;  wsp += (size_t)BSEG * CC * sizeof(float);
    float* vp   = (float*)wsp;  wsp += (size_t)BSEG * CC * sizeof(float);
    float* SVb  = (float*)wsp;  wsp += (size_t)BSEG * CC * sizeof(float);
    float* ssum = (float*)wsp;  wsp += (size_t)BSEG * CC * sizeof(float);
    short* W1q  = (short*)wsp;  wsp += (size_t)32 * 256 * 8 * sizeof(short);     // 128 KB
    short* W1o  = (short*)wsp;  wsp += (size_t)32 * 256 * 8 * sizeof(short);

    kv_proj_kernel<<<BSEG, 256, 0, stream>>>(k, v, Wk, bk, Wv, bv, kps, vp, ssum);
    wpack_kernel<<<64, 256, 0, stream>>>(Wq, Wo, W1q, W1o);

    gemm_p<0><<<GRID, 512, 0, stream>>>(
        (const void*)q, W1q, bq, (void*)attn, batch, kps, nullptr, ssum);

    sv_kernel<<<BSEG, 256, 0, stream>>>(vp, ssum, SVb);

    gemm_p<1><<<GRID, 512, 0, stream>>>(
        (const void*)attn, W1o, bo, (void*)out, batch, nullptr, SVb, nullptr);
}

// Round 15
// 127.559 us; speedup vs baseline: 1.8963x; 1.1870x over previous
//
#include <hip/hip_runtime.h>
#include <math.h>

#define N_PTS 131072
#define BSEG 64
#define CC 256
#define BM 64                    // rows per block; A tile (full K) LDS-resident
#define NSTEP 8
#define EXP_SHIFT 4.0f

#define INV_SQRT_DH 0.17677669529663687f  // 1/sqrt(32)

typedef short v8s __attribute__((ext_vector_type(8)));
typedef float v4f __attribute__((ext_vector_type(4)));
typedef int   v4i __attribute__((ext_vector_type(4)));

__device__ __forceinline__ float bf2f(unsigned short h) {
    unsigned u = ((unsigned)h) << 16;
    return __builtin_bit_cast(float, u);
}

__device__ __forceinline__ unsigned short f2bf(float f) {
    unsigned u = __builtin_bit_cast(unsigned, f);
    u += 0x7fffu + ((u >> 16) & 1u);
    return (unsigned short)(u >> 16);
}

// pack 8 fp32 -> 8 bf16 (RNE)
__device__ __forceinline__ v8s pack8(const float* x) {
    int h2[4];
    #pragma unroll
    for (int i = 0; i < 4; ++i)
        h2[i] = (int)(((unsigned)f2bf(x[2 * i + 1]) << 16) | f2bf(x[2 * i]));
    return __builtin_bit_cast(v8s, make_int4(h2[0], h2[1], h2[2], h2[3]));
}

__device__ __forceinline__ v8s as_v8s(int4 v) { return __builtin_bit_cast(v8s, v); }

// ---------------------------------------------------------------------------
// K1: kps = (k @ Wk^T + bk)/sqrt(DH) ; vp = v @ Wv^T + bv ; zero ssum
// ---------------------------------------------------------------------------
__global__ __launch_bounds__(256) void kv_proj_kernel(
    const float* __restrict__ k, const float* __restrict__ v,
    const float* __restrict__ Wk, const float* __restrict__ bk,
    const float* __restrict__ Wv, const float* __restrict__ bv,
    float* __restrict__ kps, float* __restrict__ vp, float* __restrict__ ssum) {
    int b = blockIdx.x;
    int c = threadIdx.x;
    const float4* krow  = (const float4*)(k + (size_t)b * CC);
    const float4* vrow  = (const float4*)(v + (size_t)b * CC);
    const float4* wkrow = (const float4*)(Wk + (size_t)c * CC);
    const float4* wvrow = (const float4*)(Wv + (size_t)c * CC);
    float accK = 0.f, accV = 0.f;
    #pragma unroll 8
    for (int i = 0; i < CC / 4; ++i) {
        float4 kk = krow[i], wk = wkrow[i];
        accK += kk.x * wk.x + kk.y * wk.y + kk.z * wk.z + kk.w * wk.w;
        float4 vv = vrow[i], wv = wvrow[i];
        accV += vv.x * wv.x + vv.y * wv.y + vv.z * wv.z + vv.w * wv.w;
    }
    kps[b * CC + c] = (accK + bk[c]) * INV_SQRT_DH;
    vp[b * CC + c] = accV + bv[c];
    ssum[b * CC + c] = 0.f;
}

// ---------------------------------------------------------------------------
// K1b: pack Wq/Wo into single bf16 plane, layout W1[kf(32)][n(256)][8]
// ---------------------------------------------------------------------------
__global__ __launch_bounds__(256) void wpack_kernel(
    const float* __restrict__ Wq, const float* __restrict__ Wo,
    short* __restrict__ W1q, short* __restrict__ W1o) {
    int bx = blockIdx.x;                 // 0..63
    const float* W = (bx >= 32) ? Wo : Wq;
    short* W1 = (bx >= 32) ? W1o : W1q;
    int kf = bx & 31;
    int n = threadIdx.x;
    const float* src = W + (size_t)n * CC + kf * 8;
    float4 x0 = *(const float4*)(src);
    float4 x1 = *(const float4*)(src + 4);
    float x[8] = {x0.x, x0.y, x0.z, x0.w, x1.x, x1.y, x1.z, x1.w};
    *(v8s*)&W1[((size_t)kf * 256 + n) * 8] = pack8(x);
}

// ---------------------------------------------------------------------------
// Single-plane bf16 GEMM, R9 structure: 2048 blocks x 512 thr (8 waves).
// BM=64 x BN=256; wave owns full 64 rows x a 32-col strip (mi=4, ni=2 ->
// 8 MFMA per K-step per wave, deep acc ILP). A tile (64 rows x K=256 bf16)
// staged once into a 32 KB LDS plane (2-way swizzle); one barrier; 8 K-steps
// with 1-deep single-plane B prefetch (8 VGPR); barrier; LDS-bounce epilogue.
//  MODE 0: A=q fp32 -> bf16. p = exp((acc+bq)*kps[b,c]-4) -> bf16 attn;
//          segment colsum -> ssum atomics.
//  MODE 1: A=p bf16, SV-transform at staging. Out = acc + bo (f32).
// ---------------------------------------------------------------------------
template <int MODE>
__global__ __launch_bounds__(512, 4) void gemm_r(
    const void* __restrict__ Ain, const short* __restrict__ W1,
    const float* __restrict__ bias, void* __restrict__ Outv,
    const int* __restrict__ batch, const float* __restrict__ kps,
    const float* __restrict__ SV, float* __restrict__ ssum) {

    __shared__ char lds[32768];      // 64 rows * 512B (bf16 plane)

    const int tid = threadIdx.x;
    const int lane = tid & 63;
    const int wn = tid >> 6;         // 0..7: 32-col strip
    const int kfl = lane >> 4;       // k-chunk 0..3
    const int rl = lane & 15;        // row (A) / col (B) in fragment
    const int colb = wn * 32;
    const int m0 = blockIdx.x * BM;
    const int hsw = ((rl & 7) << 2) | (rl >> 3);

    // ---- stage A tile: 4 items of 8 elements per thread, swizzled ----
    #pragma unroll
    for (int i = 0; i < 4; ++i) {
        int j = i * 512 + tid;           // 0..2047
        int row = j >> 5;                // 0..63
        int ch = j & 31;                 // 16B chunk (8 cols)
        int h = ((row & 7) << 2) | ((row >> 3) & 1);
        int off = row * 512 + ((ch ^ h) << 4);
        if (MODE == 0) {
            const v4f* ap = (const v4f*)((const float*)Ain +
                (size_t)(m0 + row) * CC + ch * 8);
            v4f x0 = __builtin_nontemporal_load(ap);
            v4f x1 = __builtin_nontemporal_load(ap + 1);
            float x[8] = {x0.x, x0.y, x0.z, x0.w, x1.x, x1.y, x1.z, x1.w};
            *(v8s*)(lds + off) = pack8(x);
        } else {
            const v4i* ap = (const v4i*)((const unsigned short*)Ain +
                (size_t)(m0 + row) * CC + ch * 8);
            v4i praw = __builtin_nontemporal_load(ap);
            v8s p = __builtin_bit_cast(v8s, praw);
            int b = batch[m0 + row];
            const float* svp = SV + (size_t)b * CC + ch * 8;
            v4f s0 = *(const v4f*)svp;
            v4f s1 = *(const v4f*)(svp + 4);
            float x[8];
            #pragma unroll
            for (int e = 0; e < 4; ++e) {
                x[e]     = bf2f((unsigned short)p[e]) * s0[e];
                x[4 + e] = bf2f((unsigned short)p[4 + e]) * s1[e];
            }
            *(v8s*)(lds + off) = pack8(x);
        }
    }

    v4f acc[4][2];
    #pragma unroll
    for (int i = 0; i < 4; ++i)
        #pragma unroll
        for (int j = 0; j < 2; ++j) acc[i][j] = (v4f){0.f, 0.f, 0.f, 0.f};

    // prefetch B for s=0 (single plane: 2 x v8s = 8 VGPR)
    v8s bcur[2];
    #pragma unroll
    for (int ni = 0; ni < 2; ++ni)
        bcur[ni] = as_v8s(*(const int4*)(W1 +
            ((size_t)kfl * 256 + colb + ni * 16 + rl) * 8));

    __syncthreads();   // barrier A: tile staged

    #pragma unroll
    for (int s = 0; s < NSTEP; ++s) {
        v8s bnx[2];
        if (s + 1 < NSTEP) {
            #pragma unroll
            for (int ni = 0; ni < 2; ++ni)
                bnx[ni] = as_v8s(*(const int4*)(W1 +
                    ((size_t)((s + 1) * 4 + kfl) * 256 + colb + ni * 16 + rl) * 8));
        }
        #pragma unroll
        for (int mi = 0; mi < 4; ++mi) {
            int abase = (mi * 16 + rl) * 512 + (((s * 4 + kfl) ^ hsw) << 4);
            v8s a = *(const v8s*)(lds + abase);
            #pragma unroll
            for (int ni = 0; ni < 2; ++ni)
                acc[mi][ni] = __builtin_amdgcn_mfma_f32_16x16x32_bf16(
                    a, bcur[ni], acc[mi][ni], 0, 0, 0);
        }
        #pragma unroll
        for (int ni = 0; ni < 2; ++ni) bcur[ni] = bnx[ni];
    }

    __syncthreads();   // barrier B: A-LDS dead -> reuse as bounce

    const float bb0 = bias[colb + rl];
    const float bb1 = bias[colb + 16 + rl];

    if (MODE == 0) {
        unsigned short* Ou = (unsigned short*)Outv;
        const int bseg = batch[m0];
        const bool fastT = (bseg == batch[m0 + BM - 1]);
        if (!fastT) {
            // slow path: segment boundary inside block (rare)
            int curb = -1;
            float r0 = 0.f, r1 = 0.f;
            #pragma unroll
            for (int mi = 0; mi < 4; ++mi)
                #pragma unroll
                for (int r4 = 0; r4 < 4; ++r4) {
                    int row = m0 + mi * 16 + kfl * 4 + r4;
                    int b = batch[row];
                    if (b != curb) {
                        if (curb >= 0) {
                            atomicAdd(&ssum[(size_t)curb * CC + colb + rl], r0);
                            atomicAdd(&ssum[(size_t)curb * CC + colb + 16 + rl], r1);
                            r0 = r1 = 0.f;
                        }
                        curb = b;
                    }
                    float k0 = kps[(size_t)b * CC + colb + rl];
                    float k1 = kps[(size_t)b * CC + colb + 16 + rl];
                    float p0 = __expf((acc[mi][0][r4] + bb0) * k0 - EXP_SHIFT);
                    float p1 = __expf((acc[mi][1][r4] + bb1) * k1 - EXP_SHIFT);
                    Ou[(size_t)row * CC + colb + rl] = f2bf(p0);
                    Ou[(size_t)row * CC + colb + 16 + rl] = f2bf(p1);
                    r0 += p0; r1 += p1;
                }
            atomicAdd(&ssum[(size_t)curb * CC + colb + rl], r0);
            atomicAdd(&ssum[(size_t)curb * CC + colb + 16 + rl], r1);
        } else {
            float k0 = kps[(size_t)bseg * CC + colb + rl];
            float k1 = kps[(size_t)bseg * CC + colb + 16 + rl];
            float cs0 = 0.f, cs1 = 0.f;
            unsigned short* lwu = (unsigned short*)lds + wn * 1024;  // 2KB region
            #pragma unroll
            for (int mi = 0; mi < 4; ++mi) {
                #pragma unroll
                for (int r4 = 0; r4 < 4; ++r4) {
                    float p0 = __expf((acc[mi][0][r4] + bb0) * k0 - EXP_SHIFT);
                    float p1 = __expf((acc[mi][1][r4] + bb1) * k1 - EXP_SHIFT);
                    cs0 += p0; cs1 += p1;
                    lwu[(kfl * 4 + r4) * 40 + rl] = f2bf(p0);
                    lwu[(kfl * 4 + r4) * 40 + 16 + rl] = f2bf(p1);
                }
                asm volatile("s_waitcnt lgkmcnt(0)" ::: "memory");
                int row16 = lane >> 2, chunk = lane & 3;
                v4i pv = *(const v4i*)&lwu[row16 * 40 + chunk * 8];
                __builtin_nontemporal_store(pv,
                    (v4i*)&Ou[(size_t)(m0 + mi * 16 + row16) * CC + colb + chunk * 8]);
                asm volatile("s_waitcnt lgkmcnt(0)" ::: "memory");
            }
            cs0 += __shfl_xor(cs0, 16); cs0 += __shfl_xor(cs0, 32);
            cs1 += __shfl_xor(cs1, 16); cs1 += __shfl_xor(cs1, 32);
            if (kfl == 0) {
                atomicAdd(&ssum[(size_t)bseg * CC + colb + rl], cs0);
                atomicAdd(&ssum[(size_t)bseg * CC + colb + 16 + rl], cs1);
            }
        }
    } else {
        float* Of = (float*)Outv;
        float* lwf = (float*)(lds + wn * 2048);   // 2KB region: 8 rows x 36 f
        #pragma unroll
        for (int mi = 0; mi < 4; ++mi)
            #pragma unroll
            for (int c = 0; c < 2; ++c) {
                if ((kfl >> 1) == c) {
                    #pragma unroll
                    for (int r4 = 0; r4 < 4; ++r4) {
                        lwf[((kfl & 1) * 4 + r4) * 36 + rl] = acc[mi][0][r4] + bb0;
                        lwf[((kfl & 1) * 4 + r4) * 36 + 16 + rl] = acc[mi][1][r4] + bb1;
                    }
                }
                asm volatile("s_waitcnt lgkmcnt(0)" ::: "memory");
                int r = lane >> 3, c4 = lane & 7;
                v4f pv = *(const v4f*)&lwf[r * 36 + c4 * 4];
                __builtin_nontemporal_store(pv,
                    (v4f*)&Of[(size_t)(m0 + mi * 16 + c * 8 + r) * CC + colb + c4 * 4]);
                asm volatile("s_waitcnt lgkmcnt(0)" ::: "memory");
            }
    }
}

// ---------------------------------------------------------------------------
// K_sv: SV[b,c] = vp[b,c] / ssum[b,c]
// ---------------------------------------------------------------------------
__global__ __launch_bounds__(256) void sv_kernel(
    const float* __restrict__ vp, const float* __restrict__ ssum,
    float* __restrict__ SV) {
    int i = blockIdx.x * 256 + threadIdx.x;
    SV[i] = vp[i] / ssum[i];
}

// ---------------------------------------------------------------------------
extern "C" void kernel_launch(void* const* d_in, const int* in_sizes, int n_in,
                              void* d_out, int out_size, void* d_ws, size_t ws_size,
                              hipStream_t stream) {
    const float* q  = (const float*)d_in[0];
    const float* k  = (const float*)d_in[1];
    const float* v  = (const float*)d_in[2];
    const int* batch = (const int*)d_in[3];
    const float* Wq = (const float*)d_in[4];
    const float* bq = (const float*)d_in[5];
    const float* Wk = (const float*)d_in[6];
    const float* bk = (const float*)d_in[7];
    const float* Wv = (const float*)d_in[8];
    const float* bv = (const float*)d_in[9];
    const float* Wo = (const float*)d_in[10];
    const float* bo = (const float*)d_in[11];
    float* out = (float*)d_out;

    char* wsp = (char*)d_ws;
    unsigned short* attn = (unsigned short*)wsp;
    wsp += (size_t)N_PTS * CC * sizeof(unsigned short);                          // 67 MB
    float* kps  = (float*)wsp;  wsp += (size_t)BSEG * CC * sizeof(float);
    float* vp   = (float*)wsp;  wsp += (size_t)BSEG * CC * sizeof(float);
    float* SVb  = (float*)wsp;  wsp += (size_t)BSEG * CC * sizeof(float);
    float* ssum = (float*)wsp;  wsp += (size_t)BSEG * CC * sizeof(float);
    short* W1q  = (short*)wsp;  wsp += (size_t)32 * 256 * 8 * sizeof(short);     // 128 KB
    short* W1o  = (short*)wsp;  wsp += (size_t)32 * 256 * 8 * sizeof(short);

    kv_proj_kernel<<<BSEG, 256, 0, stream>>>(k, v, Wk, bk, Wv, bv, kps, vp, ssum);
    wpack_kernel<<<64, 256, 0, stream>>>(Wq, Wo, W1q, W1o);

    gemm_r<0><<<N_PTS / BM, 512, 0, stream>>>(
        (const void*)q, W1q, bq, (void*)attn, batch, kps, nullptr, ssum);

    sv_kernel<<<BSEG, 256, 0, stream>>>(vp, ssum, SVb);

    gemm_r<1><<<N_PTS / BM, 512, 0, stream>>>(
        (const void*)attn, W1o, bo, (void*)out, batch, nullptr, SVb, nullptr);
}

// Round 16
// 127.321 us; speedup vs baseline: 1.8998x; 1.0019x over previous
//
#include <hip/hip_runtime.h>
#include <math.h>

#define N_PTS 131072
#define BSEG 64
#define CC 256
#define BM 128                   // rows per block; A tile (full K) LDS-resident
#define NSTEP 8
#define EXP_SHIFT 4.0f

#define INV_SQRT_DH 0.17677669529663687f  // 1/sqrt(32)

typedef short v8s __attribute__((ext_vector_type(8)));
typedef float v4f __attribute__((ext_vector_type(4)));
typedef int   v4i __attribute__((ext_vector_type(4)));

__device__ __forceinline__ float bf2f(unsigned short h) {
    unsigned u = ((unsigned)h) << 16;
    return __builtin_bit_cast(float, u);
}

__device__ __forceinline__ unsigned short f2bf(float f) {
    unsigned u = __builtin_bit_cast(unsigned, f);
    u += 0x7fffu + ((u >> 16) & 1u);
    return (unsigned short)(u >> 16);
}

// pack 8 fp32 -> 8 bf16 (RNE)
__device__ __forceinline__ v8s pack8(const float* x) {
    int h2[4];
    #pragma unroll
    for (int i = 0; i < 4; ++i)
        h2[i] = (int)(((unsigned)f2bf(x[2 * i + 1]) << 16) | f2bf(x[2 * i]));
    return __builtin_bit_cast(v8s, make_int4(h2[0], h2[1], h2[2], h2[3]));
}

__device__ __forceinline__ v8s as_v8s(int4 v) { return __builtin_bit_cast(v8s, v); }

// ---------------------------------------------------------------------------
// K1 (merged): blocks 0..63 -> kv projection row b; blocks 64..127 -> weight
// pack (Wq for 64..95, Wo for 96..127), layout W1[kf(32)][n(256)][8].
// ---------------------------------------------------------------------------
__global__ __launch_bounds__(256) void prep_kernel(
    const float* __restrict__ k, const float* __restrict__ v,
    const float* __restrict__ Wk, const float* __restrict__ bk,
    const float* __restrict__ Wv, const float* __restrict__ bv,
    const float* __restrict__ Wq, const float* __restrict__ Wo,
    float* __restrict__ kps, float* __restrict__ vp, float* __restrict__ ssum,
    short* __restrict__ W1q, short* __restrict__ W1o) {
    int bx = blockIdx.x;
    int c = threadIdx.x;
    if (bx < 64) {
        int b = bx;
        const float4* krow  = (const float4*)(k + (size_t)b * CC);
        const float4* vrow  = (const float4*)(v + (size_t)b * CC);
        const float4* wkrow = (const float4*)(Wk + (size_t)c * CC);
        const float4* wvrow = (const float4*)(Wv + (size_t)c * CC);
        float accK = 0.f, accV = 0.f;
        #pragma unroll 8
        for (int i = 0; i < CC / 4; ++i) {
            float4 kk = krow[i], wk = wkrow[i];
            accK += kk.x * wk.x + kk.y * wk.y + kk.z * wk.z + kk.w * wk.w;
            float4 vv = vrow[i], wv = wvrow[i];
            accV += vv.x * wv.x + vv.y * wv.y + vv.z * wv.z + vv.w * wv.w;
        }
        kps[b * CC + c] = (accK + bk[c]) * INV_SQRT_DH;
        vp[b * CC + c] = accV + bv[c];
        ssum[b * CC + c] = 0.f;
    } else {
        int wx = bx - 64;                    // 0..63
        const float* W = (wx >= 32) ? Wo : Wq;
        short* W1 = (wx >= 32) ? W1o : W1q;
        int kf = wx & 31;
        const float* src = W + (size_t)c * CC + kf * 8;
        float4 x0 = *(const float4*)(src);
        float4 x1 = *(const float4*)(src + 4);
        float x[8] = {x0.x, x0.y, x0.z, x0.w, x1.x, x1.y, x1.z, x1.w};
        *(v8s*)&W1[((size_t)kf * 256 + c) * 8] = pack8(x);
    }
}

// ---------------------------------------------------------------------------
// Single-plane bf16 GEMM, deep-ILP: 1024 blocks x 512 thr (8 waves).
// BM=128 x BN=256; wave owns all 128 rows x a 32-col strip (mi=8, ni=2 ->
// 16 MFMA per 2 B-loads per K-step, deep acc ILP). A tile (128 rows x K=256
// bf16) staged once into a 64 KB LDS plane (2-way swizzle); one barrier;
// 8 K-steps with 1-deep B prefetch (8 VGPR); barrier; LDS-bounce epilogue.
//  MODE 0: A=q fp32 -> bf16. p = exp((acc+bq)*kps[b,c]-4) -> bf16 attn;
//          segment colsum -> ssum atomics.
//  MODE 1: A=p bf16, SV-transform at staging. Out = acc + bo (f32).
// ---------------------------------------------------------------------------
template <int MODE>
__global__ __launch_bounds__(512, 4) void gemm_r2(
    const void* __restrict__ Ain, const short* __restrict__ W1,
    const float* __restrict__ bias, void* __restrict__ Outv,
    const int* __restrict__ batch, const float* __restrict__ kps,
    const float* __restrict__ SV, float* __restrict__ ssum) {

    __shared__ char lds[65536];      // 128 rows * 512B (bf16 plane)

    const int tid = threadIdx.x;
    const int lane = tid & 63;
    const int wn = tid >> 6;         // 0..7: 32-col strip
    const int kfl = lane >> 4;       // k-chunk 0..3
    const int rl = lane & 15;        // row (A) / col (B) in fragment
    const int colb = wn * 32;
    const int m0 = blockIdx.x * BM;
    const int hsw = ((rl & 7) << 2) | (rl >> 3);

    // ---- stage A tile: 8 items of 8 elements per thread, swizzled ----
    #pragma unroll
    for (int i = 0; i < 8; ++i) {
        int j = i * 512 + tid;           // 0..4095
        int row = j >> 5;                // 0..127
        int ch = j & 31;                 // 16B chunk (8 cols)
        int h = ((row & 7) << 2) | ((row >> 3) & 1);
        int off = row * 512 + ((ch ^ h) << 4);
        if (MODE == 0) {
            const v4f* ap = (const v4f*)((const float*)Ain +
                (size_t)(m0 + row) * CC + ch * 8);
            v4f x0 = __builtin_nontemporal_load(ap);
            v4f x1 = __builtin_nontemporal_load(ap + 1);
            float x[8] = {x0.x, x0.y, x0.z, x0.w, x1.x, x1.y, x1.z, x1.w};
            *(v8s*)(lds + off) = pack8(x);
        } else {
            const v4i* ap = (const v4i*)((const unsigned short*)Ain +
                (size_t)(m0 + row) * CC + ch * 8);
            v4i praw = __builtin_nontemporal_load(ap);
            v8s p = __builtin_bit_cast(v8s, praw);
            int b = batch[m0 + row];
            const float* svp = SV + (size_t)b * CC + ch * 8;
            v4f s0 = *(const v4f*)svp;
            v4f s1 = *(const v4f*)(svp + 4);
            float x[8];
            #pragma unroll
            for (int e = 0; e < 4; ++e) {
                x[e]     = bf2f((unsigned short)p[e]) * s0[e];
                x[4 + e] = bf2f((unsigned short)p[4 + e]) * s1[e];
            }
            *(v8s*)(lds + off) = pack8(x);
        }
    }

    v4f acc[8][2];
    #pragma unroll
    for (int i = 0; i < 8; ++i)
        #pragma unroll
        for (int j = 0; j < 2; ++j) acc[i][j] = (v4f){0.f, 0.f, 0.f, 0.f};

    // prefetch B for s=0 (single plane: 2 x v8s = 8 VGPR)
    v8s bcur[2];
    #pragma unroll
    for (int ni = 0; ni < 2; ++ni)
        bcur[ni] = as_v8s(*(const int4*)(W1 +
            ((size_t)kfl * 256 + colb + ni * 16 + rl) * 8));

    __syncthreads();   // barrier A: tile staged

    #pragma unroll
    for (int s = 0; s < NSTEP; ++s) {
        v8s bnx[2];
        if (s + 1 < NSTEP) {
            #pragma unroll
            for (int ni = 0; ni < 2; ++ni)
                bnx[ni] = as_v8s(*(const int4*)(W1 +
                    ((size_t)((s + 1) * 4 + kfl) * 256 + colb + ni * 16 + rl) * 8));
        }
        #pragma unroll
        for (int mi = 0; mi < 8; ++mi) {
            int abase = (mi * 16 + rl) * 512 + (((s * 4 + kfl) ^ hsw) << 4);
            v8s a = *(const v8s*)(lds + abase);
            #pragma unroll
            for (int ni = 0; ni < 2; ++ni)
                acc[mi][ni] = __builtin_amdgcn_mfma_f32_16x16x32_bf16(
                    a, bcur[ni], acc[mi][ni], 0, 0, 0);
        }
        #pragma unroll
        for (int ni = 0; ni < 2; ++ni) bcur[ni] = bnx[ni];
    }

    __syncthreads();   // barrier B: A-LDS dead -> reuse as bounce

    const float bb0 = bias[colb + rl];
    const float bb1 = bias[colb + 16 + rl];

    if (MODE == 0) {
        unsigned short* Ou = (unsigned short*)Outv;
        const int bseg = batch[m0];
        const bool fastT = (bseg == batch[m0 + BM - 1]);
        if (!fastT) {
            // slow path: segment boundary inside block (~6% of blocks)
            int curb = -1;
            float r0 = 0.f, r1 = 0.f;
            #pragma unroll
            for (int mi = 0; mi < 8; ++mi)
                #pragma unroll
                for (int r4 = 0; r4 < 4; ++r4) {
                    int row = m0 + mi * 16 + kfl * 4 + r4;
                    int b = batch[row];
                    if (b != curb) {
                        if (curb >= 0) {
                            atomicAdd(&ssum[(size_t)curb * CC + colb + rl], r0);
                            atomicAdd(&ssum[(size_t)curb * CC + colb + 16 + rl], r1);
                            r0 = r1 = 0.f;
                        }
                        curb = b;
                    }
                    float k0 = kps[(size_t)b * CC + colb + rl];
                    float k1 = kps[(size_t)b * CC + colb + 16 + rl];
                    float p0 = __expf((acc[mi][0][r4] + bb0) * k0 - EXP_SHIFT);
                    float p1 = __expf((acc[mi][1][r4] + bb1) * k1 - EXP_SHIFT);
                    Ou[(size_t)row * CC + colb + rl] = f2bf(p0);
                    Ou[(size_t)row * CC + colb + 16 + rl] = f2bf(p1);
                    r0 += p0; r1 += p1;
                }
            atomicAdd(&ssum[(size_t)curb * CC + colb + rl], r0);
            atomicAdd(&ssum[(size_t)curb * CC + colb + 16 + rl], r1);
        } else {
            float k0 = kps[(size_t)bseg * CC + colb + rl];
            float k1 = kps[(size_t)bseg * CC + colb + 16 + rl];
            float cs0 = 0.f, cs1 = 0.f;
            unsigned short* lwu = (unsigned short*)lds + wn * 1024;  // 2KB region
            #pragma unroll
            for (int mi = 0; mi < 8; ++mi) {
                #pragma unroll
                for (int r4 = 0; r4 < 4; ++r4) {
                    float p0 = __expf((acc[mi][0][r4] + bb0) * k0 - EXP_SHIFT);
                    float p1 = __expf((acc[mi][1][r4] + bb1) * k1 - EXP_SHIFT);
                    cs0 += p0; cs1 += p1;
                    lwu[(kfl * 4 + r4) * 40 + rl] = f2bf(p0);
                    lwu[(kfl * 4 + r4) * 40 + 16 + rl] = f2bf(p1);
                }
                asm volatile("s_waitcnt lgkmcnt(0)" ::: "memory");
                int row16 = lane >> 2, chunk = lane & 3;
                v4i pv = *(const v4i*)&lwu[row16 * 40 + chunk * 8];
                __builtin_nontemporal_store(pv,
                    (v4i*)&Ou[(size_t)(m0 + mi * 16 + row16) * CC + colb + chunk * 8]);
                asm volatile("s_waitcnt lgkmcnt(0)" ::: "memory");
            }
            cs0 += __shfl_xor(cs0, 16); cs0 += __shfl_xor(cs0, 32);
            cs1 += __shfl_xor(cs1, 16); cs1 += __shfl_xor(cs1, 32);
            if (kfl == 0) {
                atomicAdd(&ssum[(size_t)bseg * CC + colb + rl], cs0);
                atomicAdd(&ssum[(size_t)bseg * CC + colb + 16 + rl], cs1);
            }
        }
    } else {
        float* Of = (float*)Outv;
        float* lwf = (float*)(lds + wn * 2048);   // 2KB region: 8 rows x 36 f
        #pragma unroll
        for (int mi = 0; mi < 8; ++mi)
            #pragma unroll
            for (int c = 0; c < 2; ++c) {
                if ((kfl >> 1) == c) {
                    #pragma unroll
                    for (int r4 = 0; r4 < 4; ++r4) {
                        lwf[((kfl & 1) * 4 + r4) * 36 + rl] = acc[mi][0][r4] + bb0;
                        lwf[((kfl & 1) * 4 + r4) * 36 + 16 + rl] = acc[mi][1][r4] + bb1;
                    }
                }
                asm volatile("s_waitcnt lgkmcnt(0)" ::: "memory");
                int r = lane >> 3, c4 = lane & 7;
                v4f pv = *(const v4f*)&lwf[r * 36 + c4 * 4];
                __builtin_nontemporal_store(pv,
                    (v4f*)&Of[(size_t)(m0 + mi * 16 + c * 8 + r) * CC + colb + c4 * 4]);
                asm volatile("s_waitcnt lgkmcnt(0)" ::: "memory");
            }
    }
}

// ---------------------------------------------------------------------------
// K_sv: SV[b,c] = vp[b,c] / ssum[b,c]
// ---------------------------------------------------------------------------
__global__ __launch_bounds__(256) void sv_kernel(
    const float* __restrict__ vp, const float* __restrict__ ssum,
    float* __restrict__ SV) {
    int i = blockIdx.x * 256 + threadIdx.x;
    SV[i] = vp[i] / ssum[i];
}

// ---------------------------------------------------------------------------
extern "C" void kernel_launch(void* const* d_in, const int* in_sizes, int n_in,
                              void* d_out, int out_size, void* d_ws, size_t ws_size,
                              hipStream_t stream) {
    const float* q  = (const float*)d_in[0];
    const float* k  = (const float*)d_in[1];
    const float* v  = (const float*)d_in[2];
    const int* batch = (const int*)d_in[3];
    const float* Wq = (const float*)d_in[4];
    const float* bq = (const float*)d_in[5];
    const float* Wk = (const float*)d_in[6];
    const float* bk = (const float*)d_in[7];
    const float* Wv = (const float*)d_in[8];
    const float* bv = (const float*)d_in[9];
    const float* Wo = (const float*)d_in[10];
    const float* bo = (const float*)d_in[11];
    float* out = (float*)d_out;

    char* wsp = (char*)d_ws;
    unsigned short* attn = (unsigned short*)wsp;
    wsp += (size_t)N_PTS * CC * sizeof(unsigned short);                          // 67 MB
    float* kps  = (float*)wsp;  wsp += (size_t)BSEG * CC * sizeof(float);
    float* vp   = (float*)wsp;  wsp += (size_t)BSEG * CC * sizeof(float);
    float* SVb  = (float*)wsp;  wsp += (size_t)BSEG * CC * sizeof(float);
    float* ssum = (float*)wsp;  wsp += (size_t)BSEG * CC * sizeof(float);
    short* W1q  = (short*)wsp;  wsp += (size_t)32 * 256 * 8 * sizeof(short);     // 128 KB
    short* W1o  = (short*)wsp;  wsp += (size_t)32 * 256 * 8 * sizeof(short);

    prep_kernel<<<128, 256, 0, stream>>>(k, v, Wk, bk, Wv, bv, Wq, Wo,
                                         kps, vp, ssum, W1q, W1o);

    gemm_r2<0><<<N_PTS / BM, 512, 0, stream>>>(
        (const void*)q, W1q, bq, (void*)attn, batch, kps, nullptr, ssum);

    sv_kernel<<<BSEG, 256, 0, stream>>>(vp, ssum, SVb);

    gemm_r2<1><<<N_PTS / BM, 512, 0, stream>>>(
        (const void*)attn, W1o, bo, (void*)out, batch, nullptr, SVb, nullptr);
}